// Round 1
// baseline (96.599 us; speedup 1.0000x reference)
//
#include <hip/hip_runtime.h>
#include <hip/hip_bf16.h>
#include <math.h>

#define QN 900
#define TN 100
#define CN 91
#define PN 1024
#define HWD 128
#define BS 2

__device__ __forceinline__ float sigmoidf_(float x) {
    return 1.0f / (1.0f + __expf(-x));
}
__device__ __forceinline__ float softplusf_(float x) {
    // softplus(x) = max(x,0) + log(1+exp(-|x|))
    return fmaxf(x, 0.0f) + __logf(1.0f + __expf(-fabsf(x)));
}
__device__ __forceinline__ unsigned enc_ord(float f) {
    unsigned u = __float_as_uint(f);
    return (u & 0x80000000u) ? ~u : (u | 0x80000000u);
}
__device__ __forceinline__ float dec_ord(unsigned e) {
    return (e & 0x80000000u) ? __uint_as_float(e ^ 0x80000000u) : __uint_as_float(~e);
}

// ---------------------------------------------------------------------------
// Prep: blocks [0,200): tm bit-pack + popcount sums; blocks 200,201: point
// table (bilinear ints/weights) + max-slot init.
// ---------------------------------------------------------------------------
__global__ __launch_bounds__(256) void prep_kernel(
    const float* __restrict__ coords, const int* __restrict__ tmasks,
    float4* __restrict__ ptable, unsigned* __restrict__ tmw,
    float* __restrict__ tmsum, unsigned* __restrict__ maxslot)
{
    __shared__ int cnt[4];
    int bx = blockIdx.x;
    int tid = threadIdx.x;
    if (bx < BS * TN) {
        int b = bx / TN, t = bx % TN;
        const int* m = tmasks + (size_t)(b * TN + t) * (HWD * HWD);
        int wv = tid >> 6, lane = tid & 63;
        int mycnt = 0;
#pragma unroll
        for (int c = 0; c < 4; ++c) {
            int p = c * 256 + tid;
            float cx = coords[(size_t)(b * PN + p) * 2 + 0];
            float cy = coords[(size_t)(b * PN + p) * 2 + 1];
            int xi = (int)rintf(cx * (float)HWD - 0.5f);
            int yi = (int)rintf(cy * (float)HWD - 0.5f);
            bool valid = (xi >= 0) & (xi < HWD) & (yi >= 0) & (yi < HWD);
            int vv = 0;
            if (valid) vv = m[yi * HWD + xi];
            unsigned long long bal = __ballot(vv != 0);
            if (lane == 0) {
                tmw[(size_t)(b * TN + t) * 32 + c * 8 + wv * 2 + 0] = (unsigned)(bal & 0xFFFFFFFFull);
                tmw[(size_t)(b * TN + t) * 32 + c * 8 + wv * 2 + 1] = (unsigned)(bal >> 32);
                mycnt += __popcll(bal);
            }
        }
        if (lane == 0) cnt[wv] = mycnt;
        __syncthreads();
        if (tid == 0)
            tmsum[b * TN + t] = (float)((cnt[0] + cnt[1]) + (cnt[2] + cnt[3]));
    } else {
        int b = bx - BS * TN;
#pragma unroll
        for (int c = 0; c < 4; ++c) {
            int p = c * 256 + tid;
            float cx = coords[(size_t)(b * PN + p) * 2 + 0];
            float cy = coords[(size_t)(b * PN + p) * 2 + 1];
            float x = cx * (float)HWD - 0.5f;
            float y = cy * (float)HWD - 0.5f;
            float x0 = floorf(x), y0 = floorf(y);
            ptable[b * PN + p] = make_float4(__int_as_float((int)x0), __int_as_float((int)y0),
                                             x - x0, y - y0);
        }
        if (tid == 0) maxslot[b] = 0u;  // encodes "below every finite value"
    }
}

// ---------------------------------------------------------------------------
// Main: one block per (b,q). Sample 1024 points -> LDS (pm, sigmoid(pm)),
// bit-masked dual GEMM vs 100 targets, fused epilogue writes C row.
// ---------------------------------------------------------------------------
__global__ __launch_bounds__(256) void cost_kernel(
    const float* __restrict__ logits, const float4* __restrict__ pboxes,
    const int* __restrict__ labels, const float4* __restrict__ tboxes,
    const float* __restrict__ pmasks, const float4* __restrict__ ptable,
    const unsigned* __restrict__ tmw, const float* __restrict__ tmsum,
    float* __restrict__ out, unsigned* __restrict__ maxslot)
{
    __shared__ __align__(16) float2 pmsm[PN];
    __shared__ float part[8][32][8];
    __shared__ float wred[4][2];
    __shared__ float mred[256];

    int bq = blockIdx.x;
    int b = bq / QN, q = bq % QN;
    int tid = threadIdx.x;
    const float* mask = pmasks + (size_t)bq * (HWD * HWD);

    // ---- Phase A: bilinear sampling + pointwise transcendental ----
    float lsp = 0.f, lsm = 0.f;
#pragma unroll
    for (int c = 0; c < 4; ++c) {
        int p = c * 256 + tid;
        float4 pt = ptable[b * PN + p];
        int x0 = __float_as_int(pt.x);
        int y0 = __float_as_int(pt.y);
        float wx = pt.z, wy = pt.w;
        int x1 = x0 + 1, y1 = y0 + 1;
        bool vx0 = (x0 >= 0) & (x0 < HWD);
        bool vx1 = (x1 >= 0) & (x1 < HWD);
        bool vy0 = (y0 >= 0) & (y0 < HWD);
        bool vy1 = (y1 >= 0) & (y1 < HWD);
        float v00 = (vy0 & vx0) ? mask[y0 * HWD + x0] : 0.f;
        float v01 = (vy0 & vx1) ? mask[y0 * HWD + x1] : 0.f;
        float v10 = (vy1 & vx0) ? mask[y1 * HWD + x0] : 0.f;
        float v11 = (vy1 & vx1) ? mask[y1 * HWD + x1] : 0.f;
        float pm = (v00 * (1.f - wx) + v01 * wx) * (1.f - wy) +
                   (v10 * (1.f - wx) + v11 * wx) * wy;
        float sg = sigmoidf_(pm);
        pmsm[p] = make_float2(pm, sg);
        lsp += softplusf_(pm);
        lsm += sg;
    }
    // deterministic block reduction of scalars
    for (int off = 32; off > 0; off >>= 1) {
        lsp += __shfl_down(lsp, off);
        lsm += __shfl_down(lsm, off);
    }
    int wv = tid >> 6;
    if ((tid & 63) == 0) { wred[wv][0] = lsp; wred[wv][1] = lsm; }
    __syncthreads();
    float s_sp = (wred[0][0] + wred[1][0]) + (wred[2][0] + wred[3][0]);
    float s_sm = (wred[0][1] + wred[1][1]) + (wred[2][1] + wred[3][1]);

    // ---- Phase B: bit-masked dual GEMM ----
    // thread = (pc = tid>>5) p-chunk of 128 points, (ts = tid&31) -> targets
    // {ts, ts+32, ts+64, ts+96(<100)}
    int pc = tid >> 5, ts = tid & 31;
    const unsigned* rowb = tmw + (size_t)b * TN * 32;
    const float* pf = (const float*)pmsm;
    int t0 = ts, t1 = ts + 32, t2 = ts + 64, t3 = ts + 96;
    bool k3 = (t3 < TN);
    float a0 = 0, a1 = 0, a2 = 0, a3 = 0, a4 = 0, a5 = 0, a6 = 0, a7 = 0;
#pragma unroll
    for (int cc = 0; cc < 4; ++cc) {
        int p0 = pc * 128 + cc * 32;
        int wi = p0 >> 5;
        unsigned w0 = rowb[t0 * 32 + wi];
        unsigned w1 = rowb[t1 * 32 + wi];
        unsigned w2 = rowb[t2 * 32 + wi];
        unsigned w3 = k3 ? rowb[t3 * 32 + wi] : 0u;
#pragma unroll
        for (int jj = 0; jj < 16; ++jj) {
            float4 v = *(const float4*)(pf + (size_t)(p0 + jj * 2) * 2);
            float f0 = (float)(w0 & 1u); w0 >>= 1;
            float f1 = (float)(w1 & 1u); w1 >>= 1;
            float f2 = (float)(w2 & 1u); w2 >>= 1;
            float f3 = (float)(w3 & 1u); w3 >>= 1;
            a0 = fmaf(v.x, f0, a0); a1 = fmaf(v.y, f0, a1);
            a2 = fmaf(v.x, f1, a2); a3 = fmaf(v.y, f1, a3);
            a4 = fmaf(v.x, f2, a4); a5 = fmaf(v.y, f2, a5);
            a6 = fmaf(v.x, f3, a6); a7 = fmaf(v.y, f3, a7);
            float g0 = (float)(w0 & 1u); w0 >>= 1;
            float g1 = (float)(w1 & 1u); w1 >>= 1;
            float g2 = (float)(w2 & 1u); w2 >>= 1;
            float g3 = (float)(w3 & 1u); w3 >>= 1;
            a0 = fmaf(v.z, g0, a0); a1 = fmaf(v.w, g0, a1);
            a2 = fmaf(v.z, g1, a2); a3 = fmaf(v.w, g1, a3);
            a4 = fmaf(v.z, g2, a4); a5 = fmaf(v.w, g2, a5);
            a6 = fmaf(v.z, g3, a6); a7 = fmaf(v.w, g3, a7);
        }
    }
    part[pc][ts][0] = a0; part[pc][ts][1] = a1;
    part[pc][ts][2] = a2; part[pc][ts][3] = a3;
    part[pc][ts][4] = a4; part[pc][ts][5] = a5;
    part[pc][ts][6] = a6; part[pc][ts][7] = a7;
    __syncthreads();

    // ---- Epilogue: per-target fused cost ----
    float val = -INFINITY;
    if (tid < TN) {
        int t = tid, tss = t & 31, kk = t >> 5;
        float apm = 0.f, asg = 0.f;
#pragma unroll
        for (int pp = 0; pp < 8; ++pp) {
            apm += part[pp][tss][kk * 2 + 0];
            asg += part[pp][tss][kk * 2 + 1];
        }
        float ce = (s_sp - apm) * (1.0f / (float)PN);
        float tsum = tmsum[b * TN + t];
        float dice = 1.0f - (2.0f * asg + 1.0f) / (s_sm + tsum + 1.0f);

        int lab = labels[b * TN + t];
        float lg = logits[(size_t)(b * QN + q) * CN + lab];
        float pr = sigmoidf_(lg);
        float cls = 0.25f * (1.f - pr) * (1.f - pr) * softplusf_(-lg)
                  - 0.75f * pr * pr * softplusf_(lg);

        float4 pb = pboxes[b * QN + q];
        float4 tb = tboxes[b * TN + t];
        float l1 = fabsf(pb.x - tb.x) + fabsf(pb.y - tb.y) +
                   fabsf(pb.z - tb.z) + fabsf(pb.w - tb.w);

        float px1 = pb.x - 0.5f * pb.z, py1 = pb.y - 0.5f * pb.w;
        float px2 = pb.x + 0.5f * pb.z, py2 = pb.y + 0.5f * pb.w;
        float tx1 = tb.x - 0.5f * tb.z, ty1 = tb.y - 0.5f * tb.w;
        float tx2 = tb.x + 0.5f * tb.z, ty2 = tb.y + 0.5f * tb.w;
        float A1 = (px2 - px1) * (py2 - py1);
        float A2 = (tx2 - tx1) * (ty2 - ty1);
        float iw = fmaxf(fminf(px2, tx2) - fmaxf(px1, tx1), 0.f);
        float ih = fmaxf(fminf(py2, ty2) - fmaxf(py1, ty1), 0.f);
        float inter = iw * ih;
        float uni = A1 + A2 - inter;
        float iou = inter / uni;
        float cw = fmaxf(fmaxf(px2, tx2) - fminf(px1, tx1), 0.f);
        float chh = fmaxf(fmaxf(py2, ty2) - fminf(py1, ty1), 0.f);
        float area = cw * chh;
        float giou = iou - (area - uni) / area;

        float Cv = l1 + cls - giou + ce + dice;
        out[(size_t)(b * QN + q) * TN + t] = Cv;
        if (isfinite(Cv)) val = Cv;
    }
    mred[tid] = val;
    __syncthreads();
    if (tid < 64) {
        float m = fmaxf(fmaxf(mred[tid], mred[tid + 64]),
                        fmaxf(mred[tid + 128], mred[tid + 192]));
        for (int off = 32; off > 0; off >>= 1)
            m = fmaxf(m, __shfl_down(m, off));
        if (tid == 0 && m > -INFINITY)
            atomicMax(&maxslot[b], enc_ord(m));
    }
}

// ---------------------------------------------------------------------------
// Fixup: C = where(finite, C, 2*max_finite) per batch (identity when all
// entries are finite, which is the expected case).
// ---------------------------------------------------------------------------
__global__ __launch_bounds__(256) void fix_kernel(float* __restrict__ out,
                                                  const unsigned* __restrict__ maxslot)
{
    int i = blockIdx.x * blockDim.x + threadIdx.x;
    if (i >= BS * QN * TN) return;
    float v = out[i];
    if (!isfinite(v)) {
        int b = i / (QN * TN);
        out[i] = 2.0f * dec_ord(maxslot[b]);
    }
}

extern "C" void kernel_launch(void* const* d_in, const int* in_sizes, int n_in,
                              void* d_out, int out_size, void* d_ws, size_t ws_size,
                              hipStream_t stream) {
    const float* logits  = (const float*)d_in[0];
    const float4* pboxes = (const float4*)d_in[1];
    const int* labels    = (const int*)d_in[2];
    const float4* tboxes = (const float4*)d_in[3];
    const float* pmasks  = (const float*)d_in[4];
    const int* tmasks    = (const int*)d_in[5];
    const float* coords  = (const float*)d_in[6];
    float* out = (float*)d_out;

    char* ws = (char*)d_ws;
    float4* ptable    = (float4*)(ws);            // 2*1024*16   = 32768 B
    unsigned* tmw     = (unsigned*)(ws + 32768);  // 2*100*32*4  = 25600 B
    float* tmsum      = (float*)(ws + 58368);     // 2*100*4     = 800 B
    unsigned* maxslot = (unsigned*)(ws + 59200);  // 2*4         = 8 B

    hipLaunchKernelGGL(prep_kernel, dim3(BS * TN + BS), dim3(256), 0, stream,
                       coords, tmasks, ptable, tmw, tmsum, maxslot);
    hipLaunchKernelGGL(cost_kernel, dim3(BS * QN), dim3(256), 0, stream,
                       logits, pboxes, labels, tboxes, pmasks, ptable, tmw, tmsum,
                       out, maxslot);
    hipLaunchKernelGGL(fix_kernel, dim3((BS * QN * TN + 255) / 256), dim3(256), 0, stream,
                       out, maxslot);
}

// Round 2
// 90.988 us; speedup vs baseline: 1.0617x; 1.0617x over previous
//
#include <hip/hip_runtime.h>
#include <hip/hip_bf16.h>
#include <math.h>

#define QN 900
#define TN 100
#define CN 91
#define PN 1024
#define HWD 128
#define BS 2

__device__ __forceinline__ float sigmoidf_(float x) {
    return 1.0f / (1.0f + __expf(-x));
}
__device__ __forceinline__ float softplusf_(float x) {
    return fmaxf(x, 0.0f) + __logf(1.0f + __expf(-fabsf(x)));
}
__device__ __forceinline__ unsigned enc_ord(float f) {
    unsigned u = __float_as_uint(f);
    return (u & 0x80000000u) ? ~u : (u | 0x80000000u);
}
__device__ __forceinline__ float dec_ord(unsigned e) {
    return (e & 0x80000000u) ? __uint_as_float(e ^ 0x80000000u) : __uint_as_float(~e);
}
__device__ __forceinline__ unsigned short f2bf(float f) {
    unsigned u = __float_as_uint(f);
    return (unsigned short)((u + 0x7FFFu + ((u >> 16) & 1u)) >> 16);  // RNE
}
__device__ __forceinline__ float bf2f(unsigned short h) {
    return __uint_as_float(((unsigned)h) << 16);
}

// ---------------------------------------------------------------------------
// Prep: blocks [0,200): tm bit-pack + popcount sums; blocks 200,201: point
// table (bilinear ints/weights) + max-slot init.
// ---------------------------------------------------------------------------
__global__ __launch_bounds__(256) void prep_kernel(
    const float* __restrict__ coords, const int* __restrict__ tmasks,
    float4* __restrict__ ptable, unsigned* __restrict__ tmw,
    float* __restrict__ tmsum, unsigned* __restrict__ maxslot)
{
    __shared__ int cnt[4];
    int bx = blockIdx.x;
    int tid = threadIdx.x;
    if (bx < BS * TN) {
        int b = bx / TN, t = bx % TN;
        const int* m = tmasks + (size_t)(b * TN + t) * (HWD * HWD);
        int wv = tid >> 6, lane = tid & 63;
        int mycnt = 0;
#pragma unroll
        for (int c = 0; c < 4; ++c) {
            int p = c * 256 + tid;
            float cx = coords[(size_t)(b * PN + p) * 2 + 0];
            float cy = coords[(size_t)(b * PN + p) * 2 + 1];
            int xi = (int)rintf(cx * (float)HWD - 0.5f);
            int yi = (int)rintf(cy * (float)HWD - 0.5f);
            bool valid = (xi >= 0) & (xi < HWD) & (yi >= 0) & (yi < HWD);
            int vv = 0;
            if (valid) vv = m[yi * HWD + xi];
            unsigned long long bal = __ballot(vv != 0);
            if (lane == 0) {
                tmw[(size_t)(b * TN + t) * 32 + c * 8 + wv * 2 + 0] = (unsigned)(bal & 0xFFFFFFFFull);
                tmw[(size_t)(b * TN + t) * 32 + c * 8 + wv * 2 + 1] = (unsigned)(bal >> 32);
                mycnt += __popcll(bal);
            }
        }
        if (lane == 0) cnt[wv] = mycnt;
        __syncthreads();
        if (tid == 0)
            tmsum[b * TN + t] = (float)((cnt[0] + cnt[1]) + (cnt[2] + cnt[3]));
    } else {
        int b = bx - BS * TN;
#pragma unroll
        for (int c = 0; c < 4; ++c) {
            int p = c * 256 + tid;
            float cx = coords[(size_t)(b * PN + p) * 2 + 0];
            float cy = coords[(size_t)(b * PN + p) * 2 + 1];
            float x = cx * (float)HWD - 0.5f;
            float y = cy * (float)HWD - 0.5f;
            float x0 = floorf(x), y0 = floorf(y);
            ptable[b * PN + p] = make_float4(__int_as_float((int)x0), __int_as_float((int)y0),
                                             x - x0, y - y0);
        }
        if (tid == 0) maxslot[b] = 0u;
    }
}

// ---------------------------------------------------------------------------
// Main: one block per (b,q). Stage full 64KB mask -> LDS (bf16, coalesced),
// bilinear sample 1024 points from LDS, bit-masked dual GEMM vs 100 targets,
// fused epilogue writes C row.
// ---------------------------------------------------------------------------
__global__ __launch_bounds__(256) void cost_kernel(
    const float* __restrict__ logits, const float4* __restrict__ pboxes,
    const int* __restrict__ labels, const float4* __restrict__ tboxes,
    const float* __restrict__ pmasks, const float4* __restrict__ ptable,
    const unsigned* __restrict__ tmw, const float* __restrict__ tmsum,
    float* __restrict__ out, unsigned* __restrict__ maxslot)
{
    __shared__ __align__(16) unsigned short mlds[HWD * HWD];   // 32 KB
    __shared__ __align__(16) float2 pmsm[PN];                  // 8 KB
    __shared__ float part[8][32][8];                           // 8 KB
    __shared__ float wred[4][2];
    __shared__ float mred[256];

    int bq = blockIdx.x;
    int b = bq / QN, q = bq % QN;
    int tid = threadIdx.x;
    const float4* mask4 = (const float4*)(pmasks + (size_t)bq * (HWD * HWD));

    // ---- Phase 0: coalesced stage of the mask into LDS as bf16 ----
#pragma unroll
    for (int it = 0; it < 16; ++it) {
        int j = it * 256 + tid;
        float4 v = mask4[j];
        ushort4 h;
        h.x = f2bf(v.x); h.y = f2bf(v.y); h.z = f2bf(v.z); h.w = f2bf(v.w);
        *(ushort4*)&mlds[j * 4] = h;
    }
    __syncthreads();

    // ---- Phase A: bilinear sampling from LDS + pointwise transcendental ----
    float lsp = 0.f, lsm = 0.f;
#pragma unroll
    for (int c = 0; c < 4; ++c) {
        int p = c * 256 + tid;
        float4 pt = ptable[b * PN + p];
        int x0 = __float_as_int(pt.x);
        int y0 = __float_as_int(pt.y);
        float wx = pt.z, wy = pt.w;
        int x1 = x0 + 1, y1 = y0 + 1;
        bool vx0 = (x0 >= 0) & (x0 < HWD);
        bool vx1 = (x1 >= 0) & (x1 < HWD);
        bool vy0 = (y0 >= 0) & (y0 < HWD);
        bool vy1 = (y1 >= 0) & (y1 < HWD);
        float v00 = (vy0 & vx0) ? bf2f(mlds[y0 * HWD + x0]) : 0.f;
        float v01 = (vy0 & vx1) ? bf2f(mlds[y0 * HWD + x1]) : 0.f;
        float v10 = (vy1 & vx0) ? bf2f(mlds[y1 * HWD + x0]) : 0.f;
        float v11 = (vy1 & vx1) ? bf2f(mlds[y1 * HWD + x1]) : 0.f;
        float pm = (v00 * (1.f - wx) + v01 * wx) * (1.f - wy) +
                   (v10 * (1.f - wx) + v11 * wx) * wy;
        float sg = sigmoidf_(pm);
        pmsm[p] = make_float2(pm, sg);
        lsp += softplusf_(pm);
        lsm += sg;
    }
    for (int off = 32; off > 0; off >>= 1) {
        lsp += __shfl_down(lsp, off);
        lsm += __shfl_down(lsm, off);
    }
    int wv = tid >> 6;
    if ((tid & 63) == 0) { wred[wv][0] = lsp; wred[wv][1] = lsm; }
    __syncthreads();
    float s_sp = (wred[0][0] + wred[1][0]) + (wred[2][0] + wred[3][0]);
    float s_sm = (wred[0][1] + wred[1][1]) + (wred[2][1] + wred[3][1]);

    // ---- Phase B: bit-masked dual GEMM ----
    int pc = tid >> 5, ts = tid & 31;
    const unsigned* rowb = tmw + (size_t)b * TN * 32;
    const float* pf = (const float*)pmsm;
    int t0 = ts, t1 = ts + 32, t2 = ts + 64, t3 = ts + 96;
    bool k3 = (t3 < TN);
    float a0 = 0, a1 = 0, a2 = 0, a3 = 0, a4 = 0, a5 = 0, a6 = 0, a7 = 0;
#pragma unroll
    for (int cc = 0; cc < 4; ++cc) {
        int p0 = pc * 128 + cc * 32;
        int wi = p0 >> 5;
        unsigned w0 = rowb[t0 * 32 + wi];
        unsigned w1 = rowb[t1 * 32 + wi];
        unsigned w2 = rowb[t2 * 32 + wi];
        unsigned w3 = k3 ? rowb[t3 * 32 + wi] : 0u;
#pragma unroll
        for (int jj = 0; jj < 16; ++jj) {
            float4 v = *(const float4*)(pf + (size_t)(p0 + jj * 2) * 2);
            float f0 = (float)(w0 & 1u); w0 >>= 1;
            float f1 = (float)(w1 & 1u); w1 >>= 1;
            float f2 = (float)(w2 & 1u); w2 >>= 1;
            float f3 = (float)(w3 & 1u); w3 >>= 1;
            a0 = fmaf(v.x, f0, a0); a1 = fmaf(v.y, f0, a1);
            a2 = fmaf(v.x, f1, a2); a3 = fmaf(v.y, f1, a3);
            a4 = fmaf(v.x, f2, a4); a5 = fmaf(v.y, f2, a5);
            a6 = fmaf(v.x, f3, a6); a7 = fmaf(v.y, f3, a7);
            float g0 = (float)(w0 & 1u); w0 >>= 1;
            float g1 = (float)(w1 & 1u); w1 >>= 1;
            float g2 = (float)(w2 & 1u); w2 >>= 1;
            float g3 = (float)(w3 & 1u); w3 >>= 1;
            a0 = fmaf(v.z, g0, a0); a1 = fmaf(v.w, g0, a1);
            a2 = fmaf(v.z, g1, a2); a3 = fmaf(v.w, g1, a3);
            a4 = fmaf(v.z, g2, a4); a5 = fmaf(v.w, g2, a5);
            a6 = fmaf(v.z, g3, a6); a7 = fmaf(v.w, g3, a7);
        }
    }
    part[pc][ts][0] = a0; part[pc][ts][1] = a1;
    part[pc][ts][2] = a2; part[pc][ts][3] = a3;
    part[pc][ts][4] = a4; part[pc][ts][5] = a5;
    part[pc][ts][6] = a6; part[pc][ts][7] = a7;
    __syncthreads();

    // ---- Epilogue: per-target fused cost ----
    float val = -INFINITY;
    if (tid < TN) {
        int t = tid, tss = t & 31, kk = t >> 5;
        float apm = 0.f, asg = 0.f;
#pragma unroll
        for (int pp = 0; pp < 8; ++pp) {
            apm += part[pp][tss][kk * 2 + 0];
            asg += part[pp][tss][kk * 2 + 1];
        }
        float ce = (s_sp - apm) * (1.0f / (float)PN);
        float tsum = tmsum[b * TN + t];
        float dice = 1.0f - (2.0f * asg + 1.0f) / (s_sm + tsum + 1.0f);

        int lab = labels[b * TN + t];
        float lg = logits[(size_t)(b * QN + q) * CN + lab];
        float pr = sigmoidf_(lg);
        float cls = 0.25f * (1.f - pr) * (1.f - pr) * softplusf_(-lg)
                  - 0.75f * pr * pr * softplusf_(lg);

        float4 pb = pboxes[b * QN + q];
        float4 tb = tboxes[b * TN + t];
        float l1 = fabsf(pb.x - tb.x) + fabsf(pb.y - tb.y) +
                   fabsf(pb.z - tb.z) + fabsf(pb.w - tb.w);

        float px1 = pb.x - 0.5f * pb.z, py1 = pb.y - 0.5f * pb.w;
        float px2 = pb.x + 0.5f * pb.z, py2 = pb.y + 0.5f * pb.w;
        float tx1 = tb.x - 0.5f * tb.z, ty1 = tb.y - 0.5f * tb.w;
        float tx2 = tb.x + 0.5f * tb.z, ty2 = tb.y + 0.5f * tb.w;
        float A1 = (px2 - px1) * (py2 - py1);
        float A2 = (tx2 - tx1) * (ty2 - ty1);
        float iw = fmaxf(fminf(px2, tx2) - fmaxf(px1, tx1), 0.f);
        float ih = fmaxf(fminf(py2, ty2) - fmaxf(py1, ty1), 0.f);
        float inter = iw * ih;
        float uni = A1 + A2 - inter;
        float iou = inter / uni;
        float cw = fmaxf(fmaxf(px2, tx2) - fminf(px1, tx1), 0.f);
        float chh = fmaxf(fmaxf(py2, ty2) - fminf(py1, ty1), 0.f);
        float area = cw * chh;
        float giou = iou - (area - uni) / area;

        float Cv = l1 + cls - giou + ce + dice;
        out[(size_t)(b * QN + q) * TN + t] = Cv;
        if (isfinite(Cv)) val = Cv;
    }
    mred[tid] = val;
    __syncthreads();
    if (tid < 64) {
        float m = fmaxf(fmaxf(mred[tid], mred[tid + 64]),
                        fmaxf(mred[tid + 128], mred[tid + 192]));
        for (int off = 32; off > 0; off >>= 1)
            m = fmaxf(m, __shfl_down(m, off));
        if (tid == 0 && m > -INFINITY)
            atomicMax(&maxslot[b], enc_ord(m));
    }
}

// ---------------------------------------------------------------------------
// Fixup: C = where(finite, C, 2*max_finite) per batch.
// ---------------------------------------------------------------------------
__global__ __launch_bounds__(256) void fix_kernel(float* __restrict__ out,
                                                  const unsigned* __restrict__ maxslot)
{
    int i = blockIdx.x * blockDim.x + threadIdx.x;
    if (i >= BS * QN * TN) return;
    float v = out[i];
    if (!isfinite(v)) {
        int b = i / (QN * TN);
        out[i] = 2.0f * dec_ord(maxslot[b]);
    }
}

extern "C" void kernel_launch(void* const* d_in, const int* in_sizes, int n_in,
                              void* d_out, int out_size, void* d_ws, size_t ws_size,
                              hipStream_t stream) {
    const float* logits  = (const float*)d_in[0];
    const float4* pboxes = (const float4*)d_in[1];
    const int* labels    = (const int*)d_in[2];
    const float4* tboxes = (const float4*)d_in[3];
    const float* pmasks  = (const float*)d_in[4];
    const int* tmasks    = (const int*)d_in[5];
    const float* coords  = (const float*)d_in[6];
    float* out = (float*)d_out;

    char* ws = (char*)d_ws;
    float4* ptable    = (float4*)(ws);            // 32768 B
    unsigned* tmw     = (unsigned*)(ws + 32768);  // 25600 B
    float* tmsum      = (float*)(ws + 58368);     // 800 B
    unsigned* maxslot = (unsigned*)(ws + 59200);  // 8 B

    hipLaunchKernelGGL(prep_kernel, dim3(BS * TN + BS), dim3(256), 0, stream,
                       coords, tmasks, ptable, tmw, tmsum, maxslot);
    hipLaunchKernelGGL(cost_kernel, dim3(BS * QN), dim3(256), 0, stream,
                       logits, pboxes, labels, tboxes, pmasks, ptable, tmw, tmsum,
                       out, maxslot);
    hipLaunchKernelGGL(fix_kernel, dim3((BS * QN * TN + 255) / 256), dim3(256), 0, stream,
                       out, maxslot);
}

// Round 3
// 84.462 us; speedup vs baseline: 1.1437x; 1.0773x over previous
//
#include <hip/hip_runtime.h>
#include <hip/hip_bf16.h>
#include <math.h>

#define QN 900
#define TN 100
#define CN 91
#define PN 1024
#define HWD 128
#define BS 2

#define AS1 __attribute__((address_space(1)))
#define AS3 __attribute__((address_space(3)))

__device__ __forceinline__ float sigmoidf_(float x) {
    return 1.0f / (1.0f + __expf(-x));
}
__device__ __forceinline__ float softplusf_(float x) {
    return fmaxf(x, 0.0f) + __logf(1.0f + __expf(-fabsf(x)));
}
__device__ __forceinline__ unsigned enc_ord(float f) {
    unsigned u = __float_as_uint(f);
    return (u & 0x80000000u) ? ~u : (u | 0x80000000u);
}
__device__ __forceinline__ float dec_ord(unsigned e) {
    return (e & 0x80000000u) ? __uint_as_float(e ^ 0x80000000u) : __uint_as_float(~e);
}

// ---------------------------------------------------------------------------
// Prep: blocks [0,200): tm bit-pack + popcount sums; blocks 200,201: point
// table (bilinear ints/weights) + max-slot init.
// ---------------------------------------------------------------------------
__global__ __launch_bounds__(256) void prep_kernel(
    const float* __restrict__ coords, const int* __restrict__ tmasks,
    float4* __restrict__ ptable, unsigned* __restrict__ tmw,
    float* __restrict__ tmsum, unsigned* __restrict__ maxslot)
{
    __shared__ int cnt[4];
    int bx = blockIdx.x;
    int tid = threadIdx.x;
    if (bx < BS * TN) {
        int b = bx / TN, t = bx % TN;
        const int* m = tmasks + (size_t)(b * TN + t) * (HWD * HWD);
        int wv = tid >> 6, lane = tid & 63;
        int mycnt = 0;
#pragma unroll
        for (int c = 0; c < 4; ++c) {
            int p = c * 256 + tid;
            float cx = coords[(size_t)(b * PN + p) * 2 + 0];
            float cy = coords[(size_t)(b * PN + p) * 2 + 1];
            int xi = (int)rintf(cx * (float)HWD - 0.5f);
            int yi = (int)rintf(cy * (float)HWD - 0.5f);
            bool valid = (xi >= 0) & (xi < HWD) & (yi >= 0) & (yi < HWD);
            int vv = 0;
            if (valid) vv = m[yi * HWD + xi];
            unsigned long long bal = __ballot(vv != 0);
            if (lane == 0) {
                tmw[(size_t)(b * TN + t) * 32 + c * 8 + wv * 2 + 0] = (unsigned)(bal & 0xFFFFFFFFull);
                tmw[(size_t)(b * TN + t) * 32 + c * 8 + wv * 2 + 1] = (unsigned)(bal >> 32);
                mycnt += __popcll(bal);
            }
        }
        if (lane == 0) cnt[wv] = mycnt;
        __syncthreads();
        if (tid == 0)
            tmsum[b * TN + t] = (float)((cnt[0] + cnt[1]) + (cnt[2] + cnt[3]));
    } else {
        int b = bx - BS * TN;
#pragma unroll
        for (int c = 0; c < 4; ++c) {
            int p = c * 256 + tid;
            float cx = coords[(size_t)(b * PN + p) * 2 + 0];
            float cy = coords[(size_t)(b * PN + p) * 2 + 1];
            float x = cx * (float)HWD - 0.5f;
            float y = cy * (float)HWD - 0.5f;
            float x0 = floorf(x), y0 = floorf(y);
            ptable[b * PN + p] = make_float4(__int_as_float((int)x0), __int_as_float((int)y0),
                                             x - x0, y - y0);
        }
        if (tid == 0) maxslot[b] = 0u;
    }
}

// ---------------------------------------------------------------------------
// Main: one block per (b,q). Async-DMA the 64KB f32 mask into LDS
// (global_load_lds width-16, fire-and-forget -> full tile in flight),
// bilinear sample 1024 points from LDS, then ALIAS the dead mask buffer for
// pmsg/part/wred/mred and run the bit-masked dual GEMM + fused epilogue.
// ---------------------------------------------------------------------------
__global__ __launch_bounds__(256) void cost_kernel(
    const float* __restrict__ logits, const float4* __restrict__ pboxes,
    const int* __restrict__ labels, const float4* __restrict__ tboxes,
    const float* __restrict__ pmasks, const float4* __restrict__ ptable,
    const unsigned* __restrict__ tmw, const float* __restrict__ tmsum,
    float* __restrict__ out, unsigned* __restrict__ maxslot)
{
    __shared__ __align__(16) float smem[HWD * HWD];  // 64 KB, phase-aliased

    int bq = blockIdx.x;
    int b = bq / QN, q = bq % QN;
    int tid = threadIdx.x;
    int wv = tid >> 6, lane = tid & 63;
    const float* mask = pmasks + (size_t)bq * (HWD * HWD);

    // ---- Phase 0: async global->LDS staging, 16B per lane per issue ----
#pragma unroll
    for (int it = 0; it < 16; ++it) {
        const float* gsrc = mask + it * 1024 + wv * 256 + lane * 4;  // per-lane
        float* ldst = smem + it * 1024 + wv * 256;                   // wave-uniform base
        __builtin_amdgcn_global_load_lds((AS1 const void*)gsrc, (AS3 void*)ldst, 16, 0, 0);
    }

    // overlap: pull this thread's point table entries while DMA is in flight
    float4 pt[4];
#pragma unroll
    for (int c = 0; c < 4; ++c) pt[c] = ptable[b * PN + c * 256 + tid];

    asm volatile("s_waitcnt vmcnt(0)" ::: "memory");
    __syncthreads();  // mask resident

    // ---- Phase A: bilinear sampling from LDS (f32) ----
    float pmv[4], sgv[4];
    float lsp = 0.f, lsm = 0.f;
#pragma unroll
    for (int c = 0; c < 4; ++c) {
        int x0 = __float_as_int(pt[c].x);
        int y0 = __float_as_int(pt[c].y);
        float wx = pt[c].z, wy = pt[c].w;
        int x1 = x0 + 1, y1 = y0 + 1;
        bool vx0 = (x0 >= 0) & (x0 < HWD);
        bool vx1 = (x1 >= 0) & (x1 < HWD);
        bool vy0 = (y0 >= 0) & (y0 < HWD);
        bool vy1 = (y1 >= 0) & (y1 < HWD);
        float v00 = (vy0 & vx0) ? smem[y0 * HWD + x0] : 0.f;
        float v01 = (vy0 & vx1) ? smem[y0 * HWD + x1] : 0.f;
        float v10 = (vy1 & vx0) ? smem[y1 * HWD + x0] : 0.f;
        float v11 = (vy1 & vx1) ? smem[y1 * HWD + x1] : 0.f;
        float pm = (v00 * (1.f - wx) + v01 * wx) * (1.f - wy) +
                   (v10 * (1.f - wx) + v11 * wx) * wy;
        float sg = sigmoidf_(pm);
        pmv[c] = pm; sgv[c] = sg;
        lsp += softplusf_(pm);
        lsm += sg;
    }
    for (int off = 32; off > 0; off >>= 1) {
        lsp += __shfl_down(lsp, off);
        lsm += __shfl_down(lsm, off);
    }
    __syncthreads();  // everyone done READING the mask; buffer now dead

    // ---- Alias the dead mask buffer ----
    float2* pmsg = (float2*)smem;          // [0, 8KB)   : 1024 float2
    float*  part = smem + 2048;            // [8, 16KB)  : [8][32][8]
    float*  wred = smem + 4096;            // 8 floats
    float*  mred = smem + 4104;            // 256 floats

#pragma unroll
    for (int c = 0; c < 4; ++c) pmsg[c * 256 + tid] = make_float2(pmv[c], sgv[c]);
    if (lane == 0) { wred[wv * 2 + 0] = lsp; wred[wv * 2 + 1] = lsm; }
    __syncthreads();  // pmsg/wred ready

    float s_sp = (wred[0] + wred[2]) + (wred[4] + wred[6]);
    float s_sm = (wred[1] + wred[3]) + (wred[5] + wred[7]);

    // ---- Phase B: bit-masked dual GEMM ----
    int pc = tid >> 5, ts = tid & 31;
    const unsigned* rowb = tmw + (size_t)b * TN * 32;
    const float* pf = (const float*)pmsg;
    int t0 = ts, t1 = ts + 32, t2 = ts + 64, t3 = ts + 96;
    bool k3 = (t3 < TN);
    float a0 = 0, a1 = 0, a2 = 0, a3 = 0, a4 = 0, a5 = 0, a6 = 0, a7 = 0;
#pragma unroll
    for (int cc = 0; cc < 4; ++cc) {
        int p0 = pc * 128 + cc * 32;
        int wi = p0 >> 5;
        unsigned w0 = rowb[t0 * 32 + wi];
        unsigned w1 = rowb[t1 * 32 + wi];
        unsigned w2 = rowb[t2 * 32 + wi];
        unsigned w3 = k3 ? rowb[t3 * 32 + wi] : 0u;
#pragma unroll
        for (int jj = 0; jj < 16; ++jj) {
            float4 v = *(const float4*)(pf + (size_t)(p0 + jj * 2) * 2);
            float f0 = (float)(w0 & 1u); w0 >>= 1;
            float f1 = (float)(w1 & 1u); w1 >>= 1;
            float f2 = (float)(w2 & 1u); w2 >>= 1;
            float f3 = (float)(w3 & 1u); w3 >>= 1;
            a0 = fmaf(v.x, f0, a0); a1 = fmaf(v.y, f0, a1);
            a2 = fmaf(v.x, f1, a2); a3 = fmaf(v.y, f1, a3);
            a4 = fmaf(v.x, f2, a4); a5 = fmaf(v.y, f2, a5);
            a6 = fmaf(v.x, f3, a6); a7 = fmaf(v.y, f3, a7);
            float g0 = (float)(w0 & 1u); w0 >>= 1;
            float g1 = (float)(w1 & 1u); w1 >>= 1;
            float g2 = (float)(w2 & 1u); w2 >>= 1;
            float g3 = (float)(w3 & 1u); w3 >>= 1;
            a0 = fmaf(v.z, g0, a0); a1 = fmaf(v.w, g0, a1);
            a2 = fmaf(v.z, g1, a2); a3 = fmaf(v.w, g1, a3);
            a4 = fmaf(v.z, g2, a4); a5 = fmaf(v.w, g2, a5);
            a6 = fmaf(v.z, g3, a6); a7 = fmaf(v.w, g3, a7);
        }
    }
    {
        float* pr = part + (size_t)(pc * 32 + ts) * 8;
        pr[0] = a0; pr[1] = a1; pr[2] = a2; pr[3] = a3;
        pr[4] = a4; pr[5] = a5; pr[6] = a6; pr[7] = a7;
    }
    __syncthreads();  // part ready

    // ---- Epilogue: per-target fused cost ----
    float val = -INFINITY;
    if (tid < TN) {
        int t = tid, tss = t & 31, kk = t >> 5;
        float apm = 0.f, asg = 0.f;
#pragma unroll
        for (int pp = 0; pp < 8; ++pp) {
            apm += part[(size_t)(pp * 32 + tss) * 8 + kk * 2 + 0];
            asg += part[(size_t)(pp * 32 + tss) * 8 + kk * 2 + 1];
        }
        float ce = (s_sp - apm) * (1.0f / (float)PN);
        float tsum = tmsum[b * TN + t];
        float dice = 1.0f - (2.0f * asg + 1.0f) / (s_sm + tsum + 1.0f);

        int lab = labels[b * TN + t];
        float lg = logits[(size_t)(b * QN + q) * CN + lab];
        float pr = sigmoidf_(lg);
        float cls = 0.25f * (1.f - pr) * (1.f - pr) * softplusf_(-lg)
                  - 0.75f * pr * pr * softplusf_(lg);

        float4 pb = pboxes[b * QN + q];
        float4 tb = tboxes[b * TN + t];
        float l1 = fabsf(pb.x - tb.x) + fabsf(pb.y - tb.y) +
                   fabsf(pb.z - tb.z) + fabsf(pb.w - tb.w);

        float px1 = pb.x - 0.5f * pb.z, py1 = pb.y - 0.5f * pb.w;
        float px2 = pb.x + 0.5f * pb.z, py2 = pb.y + 0.5f * pb.w;
        float tx1 = tb.x - 0.5f * tb.z, ty1 = tb.y - 0.5f * tb.w;
        float tx2 = tb.x + 0.5f * tb.z, ty2 = tb.y + 0.5f * tb.w;
        float A1 = (px2 - px1) * (py2 - py1);
        float A2 = (tx2 - tx1) * (ty2 - ty1);
        float iw = fmaxf(fminf(px2, tx2) - fmaxf(px1, tx1), 0.f);
        float ih = fmaxf(fminf(py2, ty2) - fmaxf(py1, ty1), 0.f);
        float inter = iw * ih;
        float uni = A1 + A2 - inter;
        float iou = inter / uni;
        float cw = fmaxf(fmaxf(px2, tx2) - fminf(px1, tx1), 0.f);
        float chh = fmaxf(fmaxf(py2, ty2) - fminf(py1, ty1), 0.f);
        float area = cw * chh;
        float giou = iou - (area - uni) / area;

        float Cv = l1 + cls - giou + ce + dice;
        out[(size_t)(b * QN + q) * TN + t] = Cv;
        if (isfinite(Cv)) val = Cv;
    }
    mred[tid] = val;
    __syncthreads();
    if (tid < 64) {
        float m = fmaxf(fmaxf(mred[tid], mred[tid + 64]),
                        fmaxf(mred[tid + 128], mred[tid + 192]));
        for (int off = 32; off > 0; off >>= 1)
            m = fmaxf(m, __shfl_down(m, off));
        if (tid == 0 && m > -INFINITY)
            atomicMax((unsigned*)&maxslot[b], enc_ord(m));
    }
}

// ---------------------------------------------------------------------------
// Fixup: C = where(finite, C, 2*max_finite) per batch.
// ---------------------------------------------------------------------------
__global__ __launch_bounds__(256) void fix_kernel(float* __restrict__ out,
                                                  const unsigned* __restrict__ maxslot)
{
    int i = blockIdx.x * blockDim.x + threadIdx.x;
    if (i >= BS * QN * TN) return;
    float v = out[i];
    if (!isfinite(v)) {
        int b = i / (QN * TN);
        out[i] = 2.0f * dec_ord(maxslot[b]);
    }
}

extern "C" void kernel_launch(void* const* d_in, const int* in_sizes, int n_in,
                              void* d_out, int out_size, void* d_ws, size_t ws_size,
                              hipStream_t stream) {
    const float* logits  = (const float*)d_in[0];
    const float4* pboxes = (const float4*)d_in[1];
    const int* labels    = (const int*)d_in[2];
    const float4* tboxes = (const float4*)d_in[3];
    const float* pmasks  = (const float*)d_in[4];
    const int* tmasks    = (const int*)d_in[5];
    const float* coords  = (const float*)d_in[6];
    float* out = (float*)d_out;

    char* ws = (char*)d_ws;
    float4* ptable    = (float4*)(ws);            // 32768 B
    unsigned* tmw     = (unsigned*)(ws + 32768);  // 25600 B
    float* tmsum      = (float*)(ws + 58368);     // 800 B
    unsigned* maxslot = (unsigned*)(ws + 59200);  // 8 B

    hipLaunchKernelGGL(prep_kernel, dim3(BS * TN + BS), dim3(256), 0, stream,
                       coords, tmasks, ptable, tmw, tmsum, maxslot);
    hipLaunchKernelGGL(cost_kernel, dim3(BS * QN), dim3(256), 0, stream,
                       logits, pboxes, labels, tboxes, pmasks, ptable, tmw, tmsum,
                       out, maxslot);
    hipLaunchKernelGGL(fix_kernel, dim3((BS * QN * TN + 255) / 256), dim3(256), 0, stream,
                       out, maxslot);
}

// Round 4
// 74.674 us; speedup vs baseline: 1.2936x; 1.1311x over previous
//
#include <hip/hip_runtime.h>
#include <hip/hip_bf16.h>
#include <math.h>

#define QN 900
#define TN 100
#define CN 91
#define PN 1024
#define HWD 128
#define BS 2

#define AS1 __attribute__((address_space(1)))
#define AS3 __attribute__((address_space(3)))

__device__ __forceinline__ float sigmoidf_(float x) {
    return 1.0f / (1.0f + __expf(-x));
}
__device__ __forceinline__ float softplusf_(float x) {
    return fmaxf(x, 0.0f) + __logf(1.0f + __expf(-fabsf(x)));
}

// ---------------------------------------------------------------------------
// Prep: 200 blocks: tm bit-pack + popcount sums (nearest sampling).
// ---------------------------------------------------------------------------
__global__ __launch_bounds__(256) void prep_kernel(
    const float* __restrict__ coords, const int* __restrict__ tmasks,
    unsigned* __restrict__ tmw, float* __restrict__ tmsum)
{
    __shared__ int cnt[4];
    int bx = blockIdx.x;
    int tid = threadIdx.x;
    int b = bx / TN, t = bx % TN;
    const int* m = tmasks + (size_t)(b * TN + t) * (HWD * HWD);
    int wv = tid >> 6, lane = tid & 63;
    int mycnt = 0;
#pragma unroll
    for (int c = 0; c < 4; ++c) {
        int p = c * 256 + tid;
        float cx = coords[(size_t)(b * PN + p) * 2 + 0];
        float cy = coords[(size_t)(b * PN + p) * 2 + 1];
        int xi = (int)rintf(cx * (float)HWD - 0.5f);
        int yi = (int)rintf(cy * (float)HWD - 0.5f);
        bool valid = (xi >= 0) & (xi < HWD) & (yi >= 0) & (yi < HWD);
        int vv = 0;
        if (valid) vv = m[yi * HWD + xi];
        unsigned long long bal = __ballot(vv != 0);
        if (lane == 0) {
            tmw[(size_t)(b * TN + t) * 32 + c * 8 + wv * 2 + 0] = (unsigned)(bal & 0xFFFFFFFFull);
            tmw[(size_t)(b * TN + t) * 32 + c * 8 + wv * 2 + 1] = (unsigned)(bal >> 32);
            mycnt += __popcll(bal);
        }
    }
    if (lane == 0) cnt[wv] = mycnt;
    __syncthreads();
    if (tid == 0)
        tmsum[b * TN + t] = (float)((cnt[0] + cnt[1]) + (cnt[2] + cnt[3]));
}

// ---------------------------------------------------------------------------
// Main: one block per (b,q). Async-DMA the 64KB f32 mask into LDS, bilinear
// sample 1024 points, bit-masked dual GEMM vs 100 targets, fused epilogue.
// Per-block finite-max written to a PRIVATE slot (no contended atomics).
// ---------------------------------------------------------------------------
__global__ __launch_bounds__(256) void cost_kernel(
    const float* __restrict__ logits, const float4* __restrict__ pboxes,
    const int* __restrict__ labels, const float4* __restrict__ tboxes,
    const float* __restrict__ pmasks, const float2* __restrict__ coords,
    const unsigned* __restrict__ tmw, const float* __restrict__ tmsum,
    float* __restrict__ out, float* __restrict__ blockmax)
{
    __shared__ __align__(16) float smem[HWD * HWD];  // 64 KB, phase-aliased

    int bq = blockIdx.x;
    int b = bq / QN, q = bq % QN;
    int tid = threadIdx.x;
    int wv = tid >> 6, lane = tid & 63;
    const float* mask = pmasks + (size_t)bq * (HWD * HWD);

    // coords first (so their waitcnt doesn't drain the DMA queue)
    float2 cd[4];
#pragma unroll
    for (int c = 0; c < 4; ++c) cd[c] = coords[b * PN + c * 256 + tid];

    // ---- Phase 0: async global->LDS staging, 16B per lane per issue ----
#pragma unroll
    for (int it = 0; it < 16; ++it) {
        const float* gsrc = mask + it * 1024 + wv * 256 + lane * 4;  // per-lane
        float* ldst = smem + it * 1024 + wv * 256;                   // wave-uniform base
        __builtin_amdgcn_global_load_lds((AS1 const void*)gsrc, (AS3 void*)ldst, 16, 0, 0);
    }

    // bilinear decomposition while DMA is in flight
    int x0a[4], y0a[4];
    float wxa[4], wya[4];
#pragma unroll
    for (int c = 0; c < 4; ++c) {
        float x = cd[c].x * (float)HWD - 0.5f;
        float y = cd[c].y * (float)HWD - 0.5f;
        float fx = floorf(x), fy = floorf(y);
        x0a[c] = (int)fx; y0a[c] = (int)fy;
        wxa[c] = x - fx;  wya[c] = y - fy;
    }

    asm volatile("s_waitcnt vmcnt(0)" ::: "memory");
    __syncthreads();  // mask resident

    // ---- Phase A: bilinear sampling from LDS (f32) ----
    float pmv[4], sgv[4];
    float lsp = 0.f, lsm = 0.f;
#pragma unroll
    for (int c = 0; c < 4; ++c) {
        int x0 = x0a[c], y0 = y0a[c];
        float wx = wxa[c], wy = wya[c];
        int x1 = x0 + 1, y1 = y0 + 1;
        bool vx0 = (x0 >= 0) & (x0 < HWD);
        bool vx1 = (x1 >= 0) & (x1 < HWD);
        bool vy0 = (y0 >= 0) & (y0 < HWD);
        bool vy1 = (y1 >= 0) & (y1 < HWD);
        float v00 = (vy0 & vx0) ? smem[y0 * HWD + x0] : 0.f;
        float v01 = (vy0 & vx1) ? smem[y0 * HWD + x1] : 0.f;
        float v10 = (vy1 & vx0) ? smem[y1 * HWD + x0] : 0.f;
        float v11 = (vy1 & vx1) ? smem[y1 * HWD + x1] : 0.f;
        float pm = (v00 * (1.f - wx) + v01 * wx) * (1.f - wy) +
                   (v10 * (1.f - wx) + v11 * wx) * wy;
        float sg = sigmoidf_(pm);
        pmv[c] = pm; sgv[c] = sg;
        lsp += softplusf_(pm);
        lsm += sg;
    }
    for (int off = 32; off > 0; off >>= 1) {
        lsp += __shfl_down(lsp, off);
        lsm += __shfl_down(lsm, off);
    }
    __syncthreads();  // everyone done READING the mask; buffer now dead

    // ---- Alias the dead mask buffer ----
    float2* pmsg = (float2*)smem;          // [0, 8KB)   : 1024 float2
    float*  part = smem + 2048;            // [8, 16KB)  : [8][32][8]
    float*  wred = smem + 4096;            // 8 floats
    float*  mred = smem + 4104;            // 256 floats

#pragma unroll
    for (int c = 0; c < 4; ++c) pmsg[c * 256 + tid] = make_float2(pmv[c], sgv[c]);
    if (lane == 0) { wred[wv * 2 + 0] = lsp; wred[wv * 2 + 1] = lsm; }
    __syncthreads();  // pmsg/wred ready

    float s_sp = (wred[0] + wred[2]) + (wred[4] + wred[6]);
    float s_sm = (wred[1] + wred[3]) + (wred[5] + wred[7]);

    // ---- Phase B: bit-masked dual GEMM ----
    int pc = tid >> 5, ts = tid & 31;
    const unsigned* rowb = tmw + (size_t)b * TN * 32;
    const float* pf = (const float*)pmsg;
    int t0 = ts, t1 = ts + 32, t2 = ts + 64, t3 = ts + 96;
    bool k3 = (t3 < TN);
    float a0 = 0, a1 = 0, a2 = 0, a3 = 0, a4 = 0, a5 = 0, a6 = 0, a7 = 0;
#pragma unroll
    for (int cc = 0; cc < 4; ++cc) {
        int p0 = pc * 128 + cc * 32;
        int wi = p0 >> 5;
        unsigned w0 = rowb[t0 * 32 + wi];
        unsigned w1 = rowb[t1 * 32 + wi];
        unsigned w2 = rowb[t2 * 32 + wi];
        unsigned w3 = k3 ? rowb[t3 * 32 + wi] : 0u;
#pragma unroll
        for (int jj = 0; jj < 16; ++jj) {
            float4 v = *(const float4*)(pf + (size_t)(p0 + jj * 2) * 2);
            float f0 = (float)(w0 & 1u); w0 >>= 1;
            float f1 = (float)(w1 & 1u); w1 >>= 1;
            float f2 = (float)(w2 & 1u); w2 >>= 1;
            float f3 = (float)(w3 & 1u); w3 >>= 1;
            a0 = fmaf(v.x, f0, a0); a1 = fmaf(v.y, f0, a1);
            a2 = fmaf(v.x, f1, a2); a3 = fmaf(v.y, f1, a3);
            a4 = fmaf(v.x, f2, a4); a5 = fmaf(v.y, f2, a5);
            a6 = fmaf(v.x, f3, a6); a7 = fmaf(v.y, f3, a7);
            float g0 = (float)(w0 & 1u); w0 >>= 1;
            float g1 = (float)(w1 & 1u); w1 >>= 1;
            float g2 = (float)(w2 & 1u); w2 >>= 1;
            float g3 = (float)(w3 & 1u); w3 >>= 1;
            a0 = fmaf(v.z, g0, a0); a1 = fmaf(v.w, g0, a1);
            a2 = fmaf(v.z, g1, a2); a3 = fmaf(v.w, g1, a3);
            a4 = fmaf(v.z, g2, a4); a5 = fmaf(v.w, g2, a5);
            a6 = fmaf(v.z, g3, a6); a7 = fmaf(v.w, g3, a7);
        }
    }
    {
        float* pr = part + (size_t)(pc * 32 + ts) * 8;
        pr[0] = a0; pr[1] = a1; pr[2] = a2; pr[3] = a3;
        pr[4] = a4; pr[5] = a5; pr[6] = a6; pr[7] = a7;
    }
    __syncthreads();  // part ready

    // ---- Epilogue: per-target fused cost ----
    float val = -INFINITY;
    if (tid < TN) {
        int t = tid, tss = t & 31, kk = t >> 5;
        float apm = 0.f, asg = 0.f;
#pragma unroll
        for (int pp = 0; pp < 8; ++pp) {
            apm += part[(size_t)(pp * 32 + tss) * 8 + kk * 2 + 0];
            asg += part[(size_t)(pp * 32 + tss) * 8 + kk * 2 + 1];
        }
        float ce = (s_sp - apm) * (1.0f / (float)PN);
        float tsum = tmsum[b * TN + t];
        float dice = 1.0f - (2.0f * asg + 1.0f) / (s_sm + tsum + 1.0f);

        int lab = labels[b * TN + t];
        float lg = logits[(size_t)(b * QN + q) * CN + lab];
        float pr = sigmoidf_(lg);
        float cls = 0.25f * (1.f - pr) * (1.f - pr) * softplusf_(-lg)
                  - 0.75f * pr * pr * softplusf_(lg);

        float4 pb = pboxes[b * QN + q];
        float4 tb = tboxes[b * TN + t];
        float l1 = fabsf(pb.x - tb.x) + fabsf(pb.y - tb.y) +
                   fabsf(pb.z - tb.z) + fabsf(pb.w - tb.w);

        float px1 = pb.x - 0.5f * pb.z, py1 = pb.y - 0.5f * pb.w;
        float px2 = pb.x + 0.5f * pb.z, py2 = pb.y + 0.5f * pb.w;
        float tx1 = tb.x - 0.5f * tb.z, ty1 = tb.y - 0.5f * tb.w;
        float tx2 = tb.x + 0.5f * tb.z, ty2 = tb.y + 0.5f * tb.w;
        float A1 = (px2 - px1) * (py2 - py1);
        float A2 = (tx2 - tx1) * (ty2 - ty1);
        float iw = fmaxf(fminf(px2, tx2) - fmaxf(px1, tx1), 0.f);
        float ih = fmaxf(fminf(py2, ty2) - fmaxf(py1, ty1), 0.f);
        float inter = iw * ih;
        float uni = A1 + A2 - inter;
        float iou = inter / uni;
        float cw = fmaxf(fmaxf(px2, tx2) - fminf(px1, tx1), 0.f);
        float chh = fmaxf(fmaxf(py2, ty2) - fminf(py1, ty1), 0.f);
        float area = cw * chh;
        float giou = iou - (area - uni) / area;

        float Cv = l1 + cls - giou + ce + dice;
        out[(size_t)(b * QN + q) * TN + t] = Cv;
        if (isfinite(Cv)) val = Cv;
    }
    mred[tid] = val;
    __syncthreads();
    if (tid < 64) {
        float m = fmaxf(fmaxf(mred[tid], mred[tid + 64]),
                        fmaxf(mred[tid + 128], mred[tid + 192]));
        for (int off = 32; off > 0; off >>= 1)
            m = fmaxf(m, __shfl_down(m, off));
        if (tid == 0) blockmax[bq] = m;   // private slot — no contention
    }
}

// ---------------------------------------------------------------------------
// Fixup: C = where(finite, C, 2*max_finite) per batch. Fast path (all
// finite): nothing to do. Slow path: scan the 900 per-block maxes.
// ---------------------------------------------------------------------------
__global__ __launch_bounds__(256) void fix_kernel(float* __restrict__ out,
                                                  const float* __restrict__ blockmax)
{
    __shared__ int bad;
    int tid = threadIdx.x;
    int i = blockIdx.x * 256 + tid;
    bool active = (i < BS * QN * TN);
    float v = active ? out[i] : 0.0f;
    if (tid == 0) bad = 0;
    __syncthreads();
    if (!isfinite(v)) bad = 1;   // benign same-value race
    __syncthreads();
    if (!bad) return;            // uniform across block
    if (!isfinite(v)) {
        int b = i / (QN * TN);
        float m = -INFINITY;
        for (int k = 0; k < QN; ++k) m = fmaxf(m, blockmax[b * QN + k]);
        out[i] = 2.0f * m;
    }
}

extern "C" void kernel_launch(void* const* d_in, const int* in_sizes, int n_in,
                              void* d_out, int out_size, void* d_ws, size_t ws_size,
                              hipStream_t stream) {
    const float* logits  = (const float*)d_in[0];
    const float4* pboxes = (const float4*)d_in[1];
    const int* labels    = (const int*)d_in[2];
    const float4* tboxes = (const float4*)d_in[3];
    const float* pmasks  = (const float*)d_in[4];
    const int* tmasks    = (const int*)d_in[5];
    const float* coords  = (const float*)d_in[6];
    float* out = (float*)d_out;

    char* ws = (char*)d_ws;
    unsigned* tmw   = (unsigned*)(ws);          // 25600 B
    float* tmsum    = (float*)(ws + 25600);     // 800 B
    float* blockmax = (float*)(ws + 26400);     // 7200 B

    hipLaunchKernelGGL(prep_kernel, dim3(BS * TN), dim3(256), 0, stream,
                       coords, tmasks, tmw, tmsum);
    hipLaunchKernelGGL(cost_kernel, dim3(BS * QN), dim3(256), 0, stream,
                       logits, pboxes, labels, tboxes, pmasks, (const float2*)coords,
                       tmw, tmsum, out, blockmax);
    hipLaunchKernelGGL(fix_kernel, dim3((BS * QN * TN + 255) / 256), dim3(256), 0, stream,
                       out, blockmax);
}

// Round 5
// 71.768 us; speedup vs baseline: 1.3460x; 1.0405x over previous
//
#include <hip/hip_runtime.h>
#include <hip/hip_bf16.h>
#include <math.h>

#define QN 900
#define TN 100
#define CN 91
#define PN 1024
#define HWD 128
#define BS 2
#define GM 8          // masks per block
#define NBLK 225      // BS*QN/GM

#define AS1 __attribute__((address_space(1)))
#define AS3 __attribute__((address_space(3)))

// Raw barriers: NEVER __syncthreads() inside the pipelined loop (its implicit
// vmcnt(0) would drain the in-flight next-mask DMA).
#define BAR_VM()   asm volatile("s_waitcnt vmcnt(0) lgkmcnt(0)\ns_barrier" ::: "memory")
#define BAR_LGKM() asm volatile("s_waitcnt lgkmcnt(0)\ns_barrier" ::: "memory")

__device__ __forceinline__ float sigmoidf_(float x) {
    return 1.0f / (1.0f + __expf(-x));
}
__device__ __forceinline__ float softplusf_(float x) {
    return fmaxf(x, 0.0f) + __logf(1.0f + __expf(-fabsf(x)));
}

// ---------------------------------------------------------------------------
// Prep: 200 blocks: tm bit-pack + popcount sums (nearest sampling).
// ---------------------------------------------------------------------------
__global__ __launch_bounds__(256) void prep_kernel(
    const float* __restrict__ coords, const int* __restrict__ tmasks,
    unsigned* __restrict__ tmw, float* __restrict__ tmsum)
{
    __shared__ int cnt[4];
    int bx = blockIdx.x;
    int tid = threadIdx.x;
    int b = bx / TN, t = bx % TN;
    const int* m = tmasks + (size_t)(b * TN + t) * (HWD * HWD);
    int wv = tid >> 6, lane = tid & 63;
    int mycnt = 0;
#pragma unroll
    for (int c = 0; c < 4; ++c) {
        int p = c * 256 + tid;
        float cx = coords[(size_t)(b * PN + p) * 2 + 0];
        float cy = coords[(size_t)(b * PN + p) * 2 + 1];
        int xi = (int)rintf(cx * (float)HWD - 0.5f);
        int yi = (int)rintf(cy * (float)HWD - 0.5f);
        bool valid = (xi >= 0) & (xi < HWD) & (yi >= 0) & (yi < HWD);
        int vv = 0;
        if (valid) vv = m[yi * HWD + xi];
        unsigned long long bal = __ballot(vv != 0);
        if (lane == 0) {
            tmw[(size_t)(b * TN + t) * 32 + c * 8 + wv * 2 + 0] = (unsigned)(bal & 0xFFFFFFFFull);
            tmw[(size_t)(b * TN + t) * 32 + c * 8 + wv * 2 + 1] = (unsigned)(bal >> 32);
            mycnt += __popcll(bal);
        }
    }
    if (lane == 0) cnt[wv] = mycnt;
    __syncthreads();
    if (tid == 0)
        tmsum[b * TN + t] = (float)((cnt[0] + cnt[1]) + (cnt[2] + cnt[3]));
}

// ---------------------------------------------------------------------------
// Main: 225 blocks x 512 threads. Each block pipelines GM=8 masks:
// double-buffered 2x64KB LDS, DMA(m+1) in flight under compute(m).
// ---------------------------------------------------------------------------
__global__ __launch_bounds__(512) void cost_kernel(
    const float* __restrict__ logits, const float4* __restrict__ pboxes,
    const int* __restrict__ labels, const float4* __restrict__ tboxes,
    const float* __restrict__ pmasks, const float2* __restrict__ coords,
    const unsigned* __restrict__ tmw, const float* __restrict__ tmsum_,
    float* __restrict__ out, float* __restrict__ blockmax)
{
    __shared__ __align__(16) float mbuf[2][HWD * HWD];     // 128 KB
    __shared__ __align__(16) float2 pmsg[PN];              // 8 KB
    __shared__ float part[16][32][9];                      // 18 KB (padded)
    __shared__ float wred[16];
    __shared__ float wmax[8];

    const int tid = threadIdx.x;
    const int wv = tid >> 6, lane = tid & 63;
    const int pc = tid >> 5, ts = tid & 31;
    const int base = blockIdx.x * GM;

    // ---- prologue: DMA mask 0 into buffer 0 ----
    {
        const float* g = pmasks + (size_t)base * (HWD * HWD);
#pragma unroll
        for (int it = 0; it < 8; ++it)
            __builtin_amdgcn_global_load_lds(
                (AS1 const void*)(g + it * 2048 + wv * 256 + lane * 4),
                (AS3 void*)(&mbuf[0][it * 2048 + wv * 256]), 16, 0, 0);
    }

#pragma unroll 1
    for (int m = 0; m < GM; ++m) {
        const int bq = base + m;
        const int b = bq / QN, q = bq - b * QN;
        const float* mb = mbuf[m & 1];

        BAR_VM();  // DMA_m resident (also drains prev iter's stores)

        // ---- per-mask global loads, issued BEFORE next-stage DMA so the
        //      compiler's waits for them never drain the DMA queue ----
        float2 cd0 = coords[b * PN + tid];
        float2 cd1 = coords[b * PN + 512 + tid];
        const unsigned* rowb = tmw + (size_t)b * TN * 32;
        unsigned wr0[2], wr1[2], wr2[2], wr3[2];
#pragma unroll
        for (int c = 0; c < 2; ++c) {
            wr0[c] = rowb[(ts +  0) * 32 + pc * 2 + c];
            wr1[c] = rowb[(ts + 32) * 32 + pc * 2 + c];
            wr2[c] = rowb[(ts + 64) * 32 + pc * 2 + c];
            wr3[c] = (ts + 96 < TN) ? rowb[(ts + 96) * 32 + pc * 2 + c] : 0u;
        }
        float lg = 0.f, tsum = 0.f;
        float4 tb = make_float4(0, 0, 0, 0), pb = make_float4(0, 0, 0, 0);
        if (tid < TN) {
            int lab = labels[b * TN + tid];
            lg = logits[(size_t)(b * QN + q) * CN + lab];
            tsum = tmsum_[b * TN + tid];
            tb = tboxes[b * TN + tid];
            pb = pboxes[b * QN + q];
        }
        asm volatile("" ::: "memory");

        // ---- issue DMA for mask m+1 (stays in flight through compute) ----
        if (m + 1 < GM) {
            const float* g = pmasks + (size_t)(bq + 1) * (HWD * HWD);
            float* dst = &mbuf[(m + 1) & 1][0];
#pragma unroll
            for (int it = 0; it < 8; ++it)
                __builtin_amdgcn_global_load_lds(
                    (AS1 const void*)(g + it * 2048 + wv * 256 + lane * 4),
                    (AS3 void*)(dst + it * 2048 + wv * 256), 16, 0, 0);
        }
        asm volatile("" ::: "memory");

        // ---- Phase A: bilinear sample 2 points/thread from LDS ----
        float lsp = 0.f, lsm = 0.f;
#pragma unroll
        for (int c = 0; c < 2; ++c) {
            float2 cdv = (c == 0) ? cd0 : cd1;
            float x = cdv.x * (float)HWD - 0.5f;
            float y = cdv.y * (float)HWD - 0.5f;
            float fx = floorf(x), fy = floorf(y);
            int x0 = (int)fx, y0 = (int)fy;
            float wx = x - fx, wy = y - fy;
            int x1 = x0 + 1, y1 = y0 + 1;
            bool vx0 = (x0 >= 0) & (x0 < HWD);
            bool vx1 = (x1 >= 0) & (x1 < HWD);
            bool vy0 = (y0 >= 0) & (y0 < HWD);
            bool vy1 = (y1 >= 0) & (y1 < HWD);
            float v00 = (vy0 & vx0) ? mb[y0 * HWD + x0] : 0.f;
            float v01 = (vy0 & vx1) ? mb[y0 * HWD + x1] : 0.f;
            float v10 = (vy1 & vx0) ? mb[y1 * HWD + x0] : 0.f;
            float v11 = (vy1 & vx1) ? mb[y1 * HWD + x1] : 0.f;
            float pm = (v00 * (1.f - wx) + v01 * wx) * (1.f - wy) +
                       (v10 * (1.f - wx) + v11 * wx) * wy;
            float sg = sigmoidf_(pm);
            pmsg[c * 512 + tid] = make_float2(pm, sg);
            lsp += softplusf_(pm);
            lsm += sg;
        }
        for (int off = 32; off > 0; off >>= 1) {
            lsp += __shfl_down(lsp, off);
            lsm += __shfl_down(lsm, off);
        }
        if (lane == 0) { wred[wv * 2 + 0] = lsp; wred[wv * 2 + 1] = lsm; }
        BAR_LGKM();  // pmsg + wred visible; DMA_{m+1} still in flight

        float s_sp = 0.f, s_sm = 0.f;
#pragma unroll
        for (int k = 0; k < 8; ++k) { s_sp += wred[k * 2]; s_sm += wred[k * 2 + 1]; }

        // ---- Phase B: bit-masked dual GEMM (pure LDS+VALU) ----
        const float* pf = (const float*)pmsg;
        float a0 = 0, a1 = 0, a2 = 0, a3 = 0, a4 = 0, a5 = 0, a6 = 0, a7 = 0;
#pragma unroll
        for (int cc = 0; cc < 2; ++cc) {
            int p0 = pc * 64 + cc * 32;
            unsigned w0 = wr0[cc], w1 = wr1[cc], w2 = wr2[cc], w3 = wr3[cc];
#pragma unroll
            for (int jj = 0; jj < 16; ++jj) {
                float4 v = *(const float4*)(pf + (size_t)(p0 + jj * 2) * 2);
                float f0 = (float)(w0 & 1u); w0 >>= 1;
                float f1 = (float)(w1 & 1u); w1 >>= 1;
                float f2 = (float)(w2 & 1u); w2 >>= 1;
                float f3 = (float)(w3 & 1u); w3 >>= 1;
                a0 = fmaf(v.x, f0, a0); a1 = fmaf(v.y, f0, a1);
                a2 = fmaf(v.x, f1, a2); a3 = fmaf(v.y, f1, a3);
                a4 = fmaf(v.x, f2, a4); a5 = fmaf(v.y, f2, a5);
                a6 = fmaf(v.x, f3, a6); a7 = fmaf(v.y, f3, a7);
                float g0 = (float)(w0 & 1u); w0 >>= 1;
                float g1 = (float)(w1 & 1u); w1 >>= 1;
                float g2 = (float)(w2 & 1u); w2 >>= 1;
                float g3 = (float)(w3 & 1u); w3 >>= 1;
                a0 = fmaf(v.z, g0, a0); a1 = fmaf(v.w, g0, a1);
                a2 = fmaf(v.z, g1, a2); a3 = fmaf(v.w, g1, a3);
                a4 = fmaf(v.z, g2, a4); a5 = fmaf(v.w, g2, a5);
                a6 = fmaf(v.z, g3, a6); a7 = fmaf(v.w, g3, a7);
            }
        }
        part[pc][ts][0] = a0; part[pc][ts][1] = a1;
        part[pc][ts][2] = a2; part[pc][ts][3] = a3;
        part[pc][ts][4] = a4; part[pc][ts][5] = a5;
        part[pc][ts][6] = a6; part[pc][ts][7] = a7;
        BAR_LGKM();  // part visible

        // ---- Epilogue: per-target fused cost ----
        float val = -INFINITY;
        if (tid < TN) {
            int t = tid, tss = t & 31, kk = t >> 5;
            float apm = 0.f, asg = 0.f;
#pragma unroll
            for (int pp = 0; pp < 16; ++pp) {
                apm += part[pp][tss][kk * 2 + 0];
                asg += part[pp][tss][kk * 2 + 1];
            }
            float ce = (s_sp - apm) * (1.0f / (float)PN);
            float dice = 1.0f - (2.0f * asg + 1.0f) / (s_sm + tsum + 1.0f);

            float pr = sigmoidf_(lg);
            float cls = 0.25f * (1.f - pr) * (1.f - pr) * softplusf_(-lg)
                      - 0.75f * pr * pr * softplusf_(lg);

            float l1 = fabsf(pb.x - tb.x) + fabsf(pb.y - tb.y) +
                       fabsf(pb.z - tb.z) + fabsf(pb.w - tb.w);

            float px1 = pb.x - 0.5f * pb.z, py1 = pb.y - 0.5f * pb.w;
            float px2 = pb.x + 0.5f * pb.z, py2 = pb.y + 0.5f * pb.w;
            float tx1 = tb.x - 0.5f * tb.z, ty1 = tb.y - 0.5f * tb.w;
            float tx2 = tb.x + 0.5f * tb.z, ty2 = tb.y + 0.5f * tb.w;
            float A1 = (px2 - px1) * (py2 - py1);
            float A2 = (tx2 - tx1) * (ty2 - ty1);
            float iw = fmaxf(fminf(px2, tx2) - fmaxf(px1, tx1), 0.f);
            float ih = fmaxf(fminf(py2, ty2) - fmaxf(py1, ty1), 0.f);
            float inter = iw * ih;
            float uni = A1 + A2 - inter;
            float iou = inter / uni;
            float cw = fmaxf(fmaxf(px2, tx2) - fminf(px1, tx1), 0.f);
            float chh = fmaxf(fmaxf(py2, ty2) - fminf(py1, ty1), 0.f);
            float area = cw * chh;
            float giou = iou - (area - uni) / area;

            float Cv = l1 + cls - giou + ce + dice;
            out[(size_t)(b * QN + q) * TN + t] = Cv;
            if (isfinite(Cv)) val = Cv;
        }
        // per-mask finite max -> private slot
        for (int off = 32; off > 0; off >>= 1)
            val = fmaxf(val, __shfl_down(val, off));
        if (lane == 0) wmax[wv] = val;
        BAR_LGKM();  // wmax visible
        if (tid == 0) {
            float mm = wmax[0];
#pragma unroll
            for (int k = 1; k < 8; ++k) mm = fmaxf(mm, wmax[k]);
            blockmax[bq] = mm;
        }
    }
}

// ---------------------------------------------------------------------------
// Fixup: C = where(finite, C, 2*max_finite) per batch. Fast path: no-op.
// ---------------------------------------------------------------------------
__global__ __launch_bounds__(256) void fix_kernel(float* __restrict__ out,
                                                  const float* __restrict__ blockmax)
{
    __shared__ int bad;
    int tid = threadIdx.x;
    int i = blockIdx.x * 256 + tid;
    bool active = (i < BS * QN * TN);
    float v = active ? out[i] : 0.0f;
    if (tid == 0) bad = 0;
    __syncthreads();
    if (!isfinite(v)) bad = 1;   // benign same-value race
    __syncthreads();
    if (!bad) return;            // uniform across block
    if (!isfinite(v)) {
        int b = i / (QN * TN);
        float m = -INFINITY;
        for (int k = 0; k < QN; ++k) m = fmaxf(m, blockmax[b * QN + k]);
        out[i] = 2.0f * m;
    }
}

extern "C" void kernel_launch(void* const* d_in, const int* in_sizes, int n_in,
                              void* d_out, int out_size, void* d_ws, size_t ws_size,
                              hipStream_t stream) {
    const float* logits  = (const float*)d_in[0];
    const float4* pboxes = (const float4*)d_in[1];
    const int* labels    = (const int*)d_in[2];
    const float4* tboxes = (const float4*)d_in[3];
    const float* pmasks  = (const float*)d_in[4];
    const int* tmasks    = (const int*)d_in[5];
    const float* coords  = (const float*)d_in[6];
    float* out = (float*)d_out;

    char* ws = (char*)d_ws;
    unsigned* tmw   = (unsigned*)(ws);          // 25600 B
    float* tmsum    = (float*)(ws + 25600);     // 800 B
    float* blockmax = (float*)(ws + 26400);     // 7200 B

    hipLaunchKernelGGL(prep_kernel, dim3(BS * TN), dim3(256), 0, stream,
                       coords, tmasks, tmw, tmsum);
    hipLaunchKernelGGL(cost_kernel, dim3(NBLK), dim3(512), 0, stream,
                       logits, pboxes, labels, tboxes, pmasks, (const float2*)coords,
                       tmw, tmsum, out, blockmax);
    hipLaunchKernelGGL(fix_kernel, dim3((BS * QN * TN + 255) / 256), dim3(256), 0, stream,
                       out, blockmax);
}

// Round 6
// 67.816 us; speedup vs baseline: 1.4244x; 1.0583x over previous
//
#include <hip/hip_runtime.h>
#include <math.h>

#define QN 900
#define TN 100
#define CN 91
#define PN 1024
#define HWD 128
#define BS 2

__device__ __forceinline__ float sigmoidf_(float x) {
    return 1.0f / (1.0f + __expf(-x));
}
__device__ __forceinline__ float softplusf_(float x) {
    return fmaxf(x, 0.0f) + __logf(1.0f + __expf(-fabsf(x)));
}
__device__ __forceinline__ unsigned bfhi(float f) {   // RNE bf16 in HIGH 16 bits
    unsigned u = __float_as_uint(f);
    return (u + 0x7FFFu + ((u >> 16) & 1u)) & 0xFFFF0000u;
}

// ---------------------------------------------------------------------------
// stage1: blocks [0,1800): sample one (b,q) mask at 1024 points directly from
// global (16 independent scattered loads/thread -> deep MLP), write packed
// (bf16 pm | bf16 sg) plane + exact f32 row sums. blocks [1800,2000): tm
// bitmap + popcounts (nearest sampling).
// ---------------------------------------------------------------------------
__global__ __launch_bounds__(256, 5) void stage1_kernel(
    const float2* __restrict__ coords, const int* __restrict__ tmasks,
    const float* __restrict__ pmasks, unsigned* __restrict__ tmw,
    float* __restrict__ tmsum, unsigned* __restrict__ plane,
    float2* __restrict__ ssum)
{
    __shared__ float sred[8];
    __shared__ int cnt[4];
    const int bx = blockIdx.x;
    const int tid = threadIdx.x;
    const int wv = tid >> 6, lane = tid & 63;

    if (bx < BS * QN) {
        const int b = bx / QN;
        const float* mask = pmasks + (size_t)bx * (HWD * HWD);

        // ---- compute all addresses, then issue all 16 loads ----
        int a00[4], a01[4], a10[4], a11[4];
        float wxa[4], wya[4];
        unsigned fl[4];   // bit0: x0 ok, bit1: x1 ok, bit2: y0 ok, bit3: y1 ok
#pragma unroll
        for (int c = 0; c < 4; ++c) {
            float2 cd = coords[b * PN + c * 256 + tid];
            float x = cd.x * (float)HWD - 0.5f;
            float y = cd.y * (float)HWD - 0.5f;
            float fx = floorf(x), fy = floorf(y);
            int x0 = (int)fx, y0 = (int)fy;
            int x1 = x0 + 1, y1 = y0 + 1;
            wxa[c] = x - fx; wya[c] = y - fy;
            int xc0 = min(max(x0, 0), HWD - 1), xc1 = min(max(x1, 0), HWD - 1);
            int yc0 = min(max(y0, 0), HWD - 1), yc1 = min(max(y1, 0), HWD - 1);
            a00[c] = yc0 * HWD + xc0; a01[c] = yc0 * HWD + xc1;
            a10[c] = yc1 * HWD + xc0; a11[c] = yc1 * HWD + xc1;
            fl[c] = (unsigned)((x0 >= 0) & (x0 < HWD))
                  | ((unsigned)((x1 >= 0) & (x1 < HWD)) << 1)
                  | ((unsigned)(y0 >= 0) << 2)            // y0 < HWD implied by y1>=... keep exact:
                  | ((unsigned)((y0 >= 0) & (y0 < HWD)) << 2)
                  | ((unsigned)((y1 >= 0) & (y1 < HWD)) << 3);
        }
        float r00[4], r01[4], r10[4], r11[4];
#pragma unroll
        for (int c = 0; c < 4; ++c) {
            r00[c] = mask[a00[c]];
            r01[c] = mask[a01[c]];
            r10[c] = mask[a10[c]];
            r11[c] = mask[a11[c]];
        }
        float lsp = 0.f, lsm = 0.f;
#pragma unroll
        for (int c = 0; c < 4; ++c) {
            bool bx0 = fl[c] & 1u, bx1 = fl[c] & 2u, by0 = fl[c] & 4u, by1 = fl[c] & 8u;
            float v00 = (by0 && bx0) ? r00[c] : 0.f;
            float v01 = (by0 && bx1) ? r01[c] : 0.f;
            float v10 = (by1 && bx0) ? r10[c] : 0.f;
            float v11 = (by1 && bx1) ? r11[c] : 0.f;
            float wx = wxa[c], wy = wya[c];
            float pm = (v00 * (1.f - wx) + v01 * wx) * (1.f - wy) +
                       (v10 * (1.f - wx) + v11 * wx) * wy;
            float sg = sigmoidf_(pm);
            lsp += softplusf_(pm);
            lsm += sg;
            unsigned usg = bfhi(sg) >> 16;
            plane[(size_t)bx * PN + c * 256 + tid] = bfhi(pm) | usg;
        }
        for (int off = 32; off > 0; off >>= 1) {
            lsp += __shfl_down(lsp, off);
            lsm += __shfl_down(lsm, off);
        }
        if (lane == 0) { sred[wv * 2 + 0] = lsp; sred[wv * 2 + 1] = lsm; }
        __syncthreads();
        if (tid == 0)
            ssum[bx] = make_float2((sred[0] + sred[2]) + (sred[4] + sred[6]),
                                   (sred[1] + sred[3]) + (sred[5] + sred[7]));
    } else {
        const int bt = bx - BS * QN;          // [0, 200)
        const int b = bt / TN, t = bt % TN;
        const int* m = tmasks + (size_t)(b * TN + t) * (HWD * HWD);
        int mycnt = 0;
#pragma unroll
        for (int c = 0; c < 4; ++c) {
            int p = c * 256 + tid;
            float2 cd = coords[b * PN + p];
            int xi = (int)rintf(cd.x * (float)HWD - 0.5f);
            int yi = (int)rintf(cd.y * (float)HWD - 0.5f);
            bool valid = (xi >= 0) & (xi < HWD) & (yi >= 0) & (yi < HWD);
            int vv = 0;
            if (valid) vv = m[yi * HWD + xi];
            unsigned long long bal = __ballot(vv != 0);
            if (lane == 0) {
                tmw[(size_t)(b * TN + t) * 32 + c * 8 + wv * 2 + 0] = (unsigned)(bal & 0xFFFFFFFFull);
                tmw[(size_t)(b * TN + t) * 32 + c * 8 + wv * 2 + 1] = (unsigned)(bal >> 32);
                mycnt += __popcll(bal);
            }
        }
        if (lane == 0) cnt[wv] = mycnt;
        __syncthreads();
        if (tid == 0)
            tmsum[b * TN + t] = (float)((cnt[0] + cnt[1]) + (cnt[2] + cnt[3]));
    }
}

// ---------------------------------------------------------------------------
// gemm: one block (256 thr) per (b,q). Stage 4KB packed plane -> LDS,
// bit-masked dual GEMM vs 100 targets, fused epilogue.
// ---------------------------------------------------------------------------
__global__ __launch_bounds__(256, 4) void gemm_kernel(
    const float* __restrict__ logits, const float4* __restrict__ pboxes,
    const int* __restrict__ labels, const float4* __restrict__ tboxes,
    const unsigned* __restrict__ plane, const unsigned* __restrict__ tmw,
    const float* __restrict__ tmsum_, const float2* __restrict__ ssum,
    float* __restrict__ out, float* __restrict__ blockmax)
{
    __shared__ unsigned pl[PN];            // 4 KB packed (pm|sg)
    __shared__ float part[8][32][9];       // 9.2 KB (stride-9: conflict-free)
    __shared__ float mred[256];

    const int bq = blockIdx.x;
    const int b = bq / QN, q = bq - b * QN;
    const int tid = threadIdx.x;
    const int pc = tid >> 5, ts = tid & 31;

    // stage plane (coalesced uint4)
    {
        uint4 u = *(const uint4*)&plane[(size_t)bq * PN + tid * 4];
        *(uint4*)&pl[tid * 4] = u;
    }
    // per-target scalars (overlap with staging latency)
    const unsigned* rowb = tmw + (size_t)b * TN * 32;
    unsigned w0[4], w1[4], w2[4], w3[4];
#pragma unroll
    for (int g = 0; g < 4; ++g) {
        w0[g] = rowb[(ts +  0) * 32 + pc * 4 + g];
        w1[g] = rowb[(ts + 32) * 32 + pc * 4 + g];
        w2[g] = rowb[(ts + 64) * 32 + pc * 4 + g];
        w3[g] = (ts + 96 < TN) ? rowb[(ts + 96) * 32 + pc * 4 + g] : 0u;
    }
    float lg = 0.f, tsum = 0.f;
    float4 tb = make_float4(0, 0, 0, 0), pb = make_float4(0, 0, 0, 0);
    if (tid < TN) {
        int lab = labels[b * TN + tid];
        lg = logits[(size_t)(b * QN + q) * CN + lab];
        tsum = tmsum_[b * TN + tid];
        tb = tboxes[b * TN + tid];
        pb = pboxes[b * QN + q];
    }
    float2 ss = ssum[bq];
    __syncthreads();

    // ---- bit-masked dual GEMM: chunk pc (128 points) x 4 targets ----
    float a0 = 0, a1 = 0, a2 = 0, a3 = 0, a4 = 0, a5 = 0, a6 = 0, a7 = 0;
#pragma unroll
    for (int g = 0; g < 4; ++g) {
        unsigned u0 = w0[g], u1 = w1[g], u2 = w2[g], u3 = w3[g];
        int p0 = pc * 128 + g * 32;
#pragma unroll
        for (int jj = 0; jj < 8; ++jj) {
            uint4 u = *(const uint4*)&pl[p0 + jj * 4];
#pragma unroll
            for (int k = 0; k < 4; ++k) {
                unsigned uv = (k == 0) ? u.x : (k == 1) ? u.y : (k == 2) ? u.z : u.w;
                float pmv = __uint_as_float(uv & 0xFFFF0000u);
                float sgv = __uint_as_float(uv << 16);
                float f0 = (float)((u0 >> k) & 1u);
                float f1 = (float)((u1 >> k) & 1u);
                float f2 = (float)((u2 >> k) & 1u);
                float f3 = (float)((u3 >> k) & 1u);
                a0 = fmaf(pmv, f0, a0); a1 = fmaf(sgv, f0, a1);
                a2 = fmaf(pmv, f1, a2); a3 = fmaf(sgv, f1, a3);
                a4 = fmaf(pmv, f2, a4); a5 = fmaf(sgv, f2, a5);
                a6 = fmaf(pmv, f3, a6); a7 = fmaf(sgv, f3, a7);
            }
            u0 >>= 4; u1 >>= 4; u2 >>= 4; u3 >>= 4;
        }
    }
    part[pc][ts][0] = a0; part[pc][ts][1] = a1;
    part[pc][ts][2] = a2; part[pc][ts][3] = a3;
    part[pc][ts][4] = a4; part[pc][ts][5] = a5;
    part[pc][ts][6] = a6; part[pc][ts][7] = a7;
    __syncthreads();

    // ---- epilogue ----
    float val = -INFINITY;
    if (tid < TN) {
        int t = tid, tss = t & 31, kk = t >> 5;
        float apm = 0.f, asg = 0.f;
#pragma unroll
        for (int pp = 0; pp < 8; ++pp) {
            apm += part[pp][tss][kk * 2 + 0];
            asg += part[pp][tss][kk * 2 + 1];
        }
        float ce = (ss.x - apm) * (1.0f / (float)PN);
        float dice = 1.0f - (2.0f * asg + 1.0f) / (ss.y + tsum + 1.0f);

        float pr = sigmoidf_(lg);
        float cls = 0.25f * (1.f - pr) * (1.f - pr) * softplusf_(-lg)
                  - 0.75f * pr * pr * softplusf_(lg);

        float l1 = fabsf(pb.x - tb.x) + fabsf(pb.y - tb.y) +
                   fabsf(pb.z - tb.z) + fabsf(pb.w - tb.w);

        float px1 = pb.x - 0.5f * pb.z, py1 = pb.y - 0.5f * pb.w;
        float px2 = pb.x + 0.5f * pb.z, py2 = pb.y + 0.5f * pb.w;
        float tx1 = tb.x - 0.5f * tb.z, ty1 = tb.y - 0.5f * tb.w;
        float tx2 = tb.x + 0.5f * tb.z, ty2 = tb.y + 0.5f * tb.w;
        float A1 = (px2 - px1) * (py2 - py1);
        float A2 = (tx2 - tx1) * (ty2 - ty1);
        float iw = fmaxf(fminf(px2, tx2) - fmaxf(px1, tx1), 0.f);
        float ih = fmaxf(fminf(py2, ty2) - fmaxf(py1, ty1), 0.f);
        float inter = iw * ih;
        float uni = A1 + A2 - inter;
        float iou = inter / uni;
        float cw = fmaxf(fmaxf(px2, tx2) - fminf(px1, tx1), 0.f);
        float chh = fmaxf(fmaxf(py2, ty2) - fminf(py1, ty1), 0.f);
        float area = cw * chh;
        float giou = iou - (area - uni) / area;

        float Cv = l1 + cls - giou + ce + dice;
        out[(size_t)(b * QN + q) * TN + t] = Cv;
        if (isfinite(Cv)) val = Cv;
    }
    mred[tid] = val;
    __syncthreads();
    if (tid < 64) {
        float m = fmaxf(fmaxf(mred[tid], mred[tid + 64]),
                        fmaxf(mred[tid + 128], mred[tid + 192]));
        for (int off = 32; off > 0; off >>= 1)
            m = fmaxf(m, __shfl_down(m, off));
        if (tid == 0) blockmax[bq] = m;
    }
}

// ---------------------------------------------------------------------------
// Fixup: C = where(finite, C, 2*max_finite) per batch. Fast path: no-op.
// ---------------------------------------------------------------------------
__global__ __launch_bounds__(256) void fix_kernel(float* __restrict__ out,
                                                  const float* __restrict__ blockmax)
{
    __shared__ int bad;
    int tid = threadIdx.x;
    int i = blockIdx.x * 256 + tid;
    bool active = (i < BS * QN * TN);
    float v = active ? out[i] : 0.0f;
    if (tid == 0) bad = 0;
    __syncthreads();
    if (!isfinite(v)) bad = 1;   // benign same-value race
    __syncthreads();
    if (!bad) return;            // uniform across block
    if (!isfinite(v)) {
        int b = i / (QN * TN);
        float m = -INFINITY;
        for (int k = 0; k < QN; ++k) m = fmaxf(m, blockmax[b * QN + k]);
        out[i] = 2.0f * m;
    }
}

extern "C" void kernel_launch(void* const* d_in, const int* in_sizes, int n_in,
                              void* d_out, int out_size, void* d_ws, size_t ws_size,
                              hipStream_t stream) {
    const float* logits  = (const float*)d_in[0];
    const float4* pboxes = (const float4*)d_in[1];
    const int* labels    = (const int*)d_in[2];
    const float4* tboxes = (const float4*)d_in[3];
    const float* pmasks  = (const float*)d_in[4];
    const int* tmasks    = (const int*)d_in[5];
    const float* coords  = (const float*)d_in[6];
    float* out = (float*)d_out;

    char* ws = (char*)d_ws;
    unsigned* tmw   = (unsigned*)(ws);            // 25600 B
    float* tmsum    = (float*)(ws + 25600);       // 800 B
    float* blockmax = (float*)(ws + 26400);       // 7200 B
    float2* ssum    = (float2*)(ws + 33600);      // 14400 B
    unsigned* plane = (unsigned*)(ws + 49152);    // 1800*4096 = 7372800 B

    hipLaunchKernelGGL(stage1_kernel, dim3(BS * QN + BS * TN), dim3(256), 0, stream,
                       (const float2*)coords, tmasks, pmasks, tmw, tmsum, plane, ssum);
    hipLaunchKernelGGL(gemm_kernel, dim3(BS * QN), dim3(256), 0, stream,
                       logits, pboxes, labels, tboxes, plane, tmw, tmsum, ssum,
                       out, blockmax);
    hipLaunchKernelGGL(fix_kernel, dim3((BS * QN * TN + 255) / 256), dim3(256), 0, stream,
                       out, blockmax);
}

// Round 7
// 53.903 us; speedup vs baseline: 1.7921x; 1.2581x over previous
//
#include <hip/hip_runtime.h>
#include <math.h>

#define QN 900
#define TN 100
#define CN 91
#define PN 1024
#define HWD 128
#define BS 2

__device__ __forceinline__ float sigmoidf_(float x) {
    return 1.0f / (1.0f + __expf(-x));
}
__device__ __forceinline__ float softplusf_(float x) {
    return fmaxf(x, 0.0f) + __logf(1.0f + __expf(-fabsf(x)));
}
__device__ __forceinline__ unsigned bfhi(float f) {   // RNE bf16 in HIGH 16 bits
    unsigned u = __float_as_uint(f);
    return (u + 0x7FFFu + ((u >> 16) & 1u)) & 0xFFFF0000u;
}

// ---------------------------------------------------------------------------
// Prep: 200 blocks: tm bit-pack + popcount sums (nearest sampling).
// ---------------------------------------------------------------------------
__global__ __launch_bounds__(256) void prep_kernel(
    const float2* __restrict__ coords, const int* __restrict__ tmasks,
    unsigned* __restrict__ tmw, float* __restrict__ tmsum)
{
    __shared__ int cnt[4];
    const int bx = blockIdx.x;
    const int tid = threadIdx.x;
    const int wv = tid >> 6, lane = tid & 63;
    const int b = bx / TN, t = bx % TN;
    const int* m = tmasks + (size_t)(b * TN + t) * (HWD * HWD);
    // addresses first, loads batched
    int addr[4]; unsigned vld[4];
#pragma unroll
    for (int c = 0; c < 4; ++c) {
        float2 cd = coords[b * PN + c * 256 + tid];
        int xi = (int)rintf(cd.x * (float)HWD - 0.5f);
        int yi = (int)rintf(cd.y * (float)HWD - 0.5f);
        vld[c] = (xi >= 0) & (xi < HWD) & (yi >= 0) & (yi < HWD);
        addr[c] = min(max(yi, 0), HWD - 1) * HWD + min(max(xi, 0), HWD - 1);
    }
    int rv[4];
#pragma unroll
    for (int c = 0; c < 4; ++c) rv[c] = m[addr[c]];
    int mycnt = 0;
#pragma unroll
    for (int c = 0; c < 4; ++c) {
        unsigned long long bal = __ballot(vld[c] && (rv[c] != 0));
        if (lane == 0) {
            tmw[(size_t)(b * TN + t) * 32 + c * 8 + wv * 2 + 0] = (unsigned)(bal & 0xFFFFFFFFull);
            tmw[(size_t)(b * TN + t) * 32 + c * 8 + wv * 2 + 1] = (unsigned)(bal >> 32);
            mycnt += __popcll(bal);
        }
    }
    if (lane == 0) cnt[wv] = mycnt;
    __syncthreads();
    if (tid == 0)
        tmsum[b * TN + t] = (float)((cnt[0] + cnt[1]) + (cnt[2] + cnt[3]));
}

// ---------------------------------------------------------------------------
// Main: one block (256 thr) per (b,q). Batched scattered sampling from global
// (16 loads in flight before first use), pm/sg packed bf16 -> 4KB LDS,
// bit-masked dual GEMM vs 100 targets, fused epilogue. LDS ~14.5 KB,
// 4 blocks/CU -> cross-block latency hiding.
// ---------------------------------------------------------------------------
__global__ __launch_bounds__(256, 4) void main_kernel(
    const float* __restrict__ logits, const float4* __restrict__ pboxes,
    const int* __restrict__ labels, const float4* __restrict__ tboxes,
    const float* __restrict__ pmasks, const float2* __restrict__ coords,
    const unsigned* __restrict__ tmw, const float* __restrict__ tmsum_,
    float* __restrict__ out, float* __restrict__ blockmax)
{
    __shared__ unsigned pl[PN];            // 4 KB packed (bf16 pm | bf16 sg)
    __shared__ float part[8][32][9];       // 9.2 KB (stride-9: conflict-free)
    __shared__ float sred[8];
    __shared__ float mred[256];

    const int bq = blockIdx.x;
    const int b = bq / QN, q = bq - b * QN;
    const int tid = threadIdx.x;
    const int wv = tid >> 6, lane = tid & 63;
    const int pc = tid >> 5, ts = tid & 31;
    const float* mask = pmasks + (size_t)bq * (HWD * HWD);

    // ---- addresses for 4 points/thread ----
    int a00[4], a01[4], a10[4], a11[4];
    float wxa[4], wya[4];
    unsigned fl[4];
#pragma unroll
    for (int c = 0; c < 4; ++c) {
        float2 cd = coords[b * PN + c * 256 + tid];
        float x = cd.x * (float)HWD - 0.5f;
        float y = cd.y * (float)HWD - 0.5f;
        float fx = floorf(x), fy = floorf(y);
        int x0 = (int)fx, y0 = (int)fy;
        int x1 = x0 + 1, y1 = y0 + 1;
        wxa[c] = x - fx; wya[c] = y - fy;
        int xc0 = min(max(x0, 0), HWD - 1), xc1 = min(max(x1, 0), HWD - 1);
        int yc0 = min(max(y0, 0), HWD - 1), yc1 = min(max(y1, 0), HWD - 1);
        a00[c] = yc0 * HWD + xc0; a01[c] = yc0 * HWD + xc1;
        a10[c] = yc1 * HWD + xc0; a11[c] = yc1 * HWD + xc1;
        fl[c] = (unsigned)((x0 >= 0) & (x0 < HWD))
              | ((unsigned)((x1 >= 0) & (x1 < HWD)) << 1)
              | ((unsigned)((y0 >= 0) & (y0 < HWD)) << 2)
              | ((unsigned)((y1 >= 0) & (y1 < HWD)) << 3);
    }

    // ---- issue ALL 16 scattered loads up front ----
    float r00[4], r01[4], r10[4], r11[4];
#pragma unroll
    for (int c = 0; c < 4; ++c) {
        r00[c] = mask[a00[c]];
        r01[c] = mask[a01[c]];
        r10[c] = mask[a10[c]];
        r11[c] = mask[a11[c]];
    }

    // ---- under the shadow: tmw words + epilogue scalars ----
    const unsigned* rowb = tmw + (size_t)b * TN * 32;
    unsigned w0[4], w1[4], w2[4], w3[4];
#pragma unroll
    for (int g = 0; g < 4; ++g) {
        w0[g] = rowb[(ts +  0) * 32 + pc * 4 + g];
        w1[g] = rowb[(ts + 32) * 32 + pc * 4 + g];
        w2[g] = rowb[(ts + 64) * 32 + pc * 4 + g];
        w3[g] = (ts + 96 < TN) ? rowb[(ts + 96) * 32 + pc * 4 + g] : 0u;
    }
    float lg = 0.f, tsum = 0.f;
    float4 tb = make_float4(0, 0, 0, 0), pb = make_float4(0, 0, 0, 0);
    if (tid < TN) {
        int lab = labels[b * TN + tid];
        lg = logits[(size_t)(b * QN + q) * CN + lab];
        tsum = tmsum_[b * TN + tid];
        tb = tboxes[b * TN + tid];
        pb = pboxes[b * QN + q];
    }

    // ---- bilinear combine + pointwise transcendental -> packed LDS ----
    float lsp = 0.f, lsm = 0.f;
#pragma unroll
    for (int c = 0; c < 4; ++c) {
        bool bx0 = fl[c] & 1u, bx1 = fl[c] & 2u, by0 = fl[c] & 4u, by1 = fl[c] & 8u;
        float v00 = (by0 && bx0) ? r00[c] : 0.f;
        float v01 = (by0 && bx1) ? r01[c] : 0.f;
        float v10 = (by1 && bx0) ? r10[c] : 0.f;
        float v11 = (by1 && bx1) ? r11[c] : 0.f;
        float wx = wxa[c], wy = wya[c];
        float pm = (v00 * (1.f - wx) + v01 * wx) * (1.f - wy) +
                   (v10 * (1.f - wx) + v11 * wx) * wy;
        float sg = sigmoidf_(pm);
        lsp += softplusf_(pm);
        lsm += sg;
        pl[c * 256 + tid] = bfhi(pm) | (bfhi(sg) >> 16);
    }
    for (int off = 32; off > 0; off >>= 1) {
        lsp += __shfl_down(lsp, off);
        lsm += __shfl_down(lsm, off);
    }
    if (lane == 0) { sred[wv * 2 + 0] = lsp; sred[wv * 2 + 1] = lsm; }
    __syncthreads();
    float s_sp = (sred[0] + sred[2]) + (sred[4] + sred[6]);
    float s_sm = (sred[1] + sred[3]) + (sred[5] + sred[7]);

    // ---- bit-masked dual GEMM: chunk pc (128 points) x 4 targets ----
    float a0 = 0, a1 = 0, a2 = 0, a3 = 0, a4 = 0, a5 = 0, a6 = 0, a7 = 0;
#pragma unroll
    for (int g = 0; g < 4; ++g) {
        unsigned u0 = w0[g], u1 = w1[g], u2 = w2[g], u3 = w3[g];
        int p0 = pc * 128 + g * 32;
#pragma unroll
        for (int jj = 0; jj < 8; ++jj) {
            uint4 u = *(const uint4*)&pl[p0 + jj * 4];   // broadcast within half-wave
#pragma unroll
            for (int k = 0; k < 4; ++k) {
                unsigned uv = (k == 0) ? u.x : (k == 1) ? u.y : (k == 2) ? u.z : u.w;
                float pmv = __uint_as_float(uv & 0xFFFF0000u);
                float sgv = __uint_as_float(uv << 16);
                float f0 = (float)((u0 >> k) & 1u);
                float f1 = (float)((u1 >> k) & 1u);
                float f2 = (float)((u2 >> k) & 1u);
                float f3 = (float)((u3 >> k) & 1u);
                a0 = fmaf(pmv, f0, a0); a1 = fmaf(sgv, f0, a1);
                a2 = fmaf(pmv, f1, a2); a3 = fmaf(sgv, f1, a3);
                a4 = fmaf(pmv, f2, a4); a5 = fmaf(sgv, f2, a5);
                a6 = fmaf(pmv, f3, a6); a7 = fmaf(sgv, f3, a7);
            }
            u0 >>= 4; u1 >>= 4; u2 >>= 4; u3 >>= 4;
        }
    }
    part[pc][ts][0] = a0; part[pc][ts][1] = a1;
    part[pc][ts][2] = a2; part[pc][ts][3] = a3;
    part[pc][ts][4] = a4; part[pc][ts][5] = a5;
    part[pc][ts][6] = a6; part[pc][ts][7] = a7;
    __syncthreads();

    // ---- epilogue ----
    float val = -INFINITY;
    if (tid < TN) {
        int t = tid, tss = t & 31, kk = t >> 5;
        float apm = 0.f, asg = 0.f;
#pragma unroll
        for (int pp = 0; pp < 8; ++pp) {
            apm += part[pp][tss][kk * 2 + 0];
            asg += part[pp][tss][kk * 2 + 1];
        }
        float ce = (s_sp - apm) * (1.0f / (float)PN);
        float dice = 1.0f - (2.0f * asg + 1.0f) / (s_sm + tsum + 1.0f);

        float pr = sigmoidf_(lg);
        float cls = 0.25f * (1.f - pr) * (1.f - pr) * softplusf_(-lg)
                  - 0.75f * pr * pr * softplusf_(lg);

        float l1 = fabsf(pb.x - tb.x) + fabsf(pb.y - tb.y) +
                   fabsf(pb.z - tb.z) + fabsf(pb.w - tb.w);

        float px1 = pb.x - 0.5f * pb.z, py1 = pb.y - 0.5f * pb.w;
        float px2 = pb.x + 0.5f * pb.z, py2 = pb.y + 0.5f * pb.w;
        float tx1 = tb.x - 0.5f * tb.z, ty1 = tb.y - 0.5f * tb.w;
        float tx2 = tb.x + 0.5f * tb.z, ty2 = tb.y + 0.5f * tb.w;
        float A1 = (px2 - px1) * (py2 - py1);
        float A2 = (tx2 - tx1) * (ty2 - ty1);
        float iw = fmaxf(fminf(px2, tx2) - fmaxf(px1, tx1), 0.f);
        float ih = fmaxf(fminf(py2, ty2) - fmaxf(py1, ty1), 0.f);
        float inter = iw * ih;
        float uni = A1 + A2 - inter;
        float iou = inter / uni;
        float cw = fmaxf(fmaxf(px2, tx2) - fminf(px1, tx1), 0.f);
        float chh = fmaxf(fmaxf(py2, ty2) - fminf(py1, ty1), 0.f);
        float area = cw * chh;
        float giou = iou - (area - uni) / area;

        float Cv = l1 + cls - giou + ce + dice;
        out[(size_t)(b * QN + q) * TN + t] = Cv;
        if (isfinite(Cv)) val = Cv;
    }
    mred[tid] = val;
    __syncthreads();
    if (tid < 64) {
        float m = fmaxf(fmaxf(mred[tid], mred[tid + 64]),
                        fmaxf(mred[tid + 128], mred[tid + 192]));
        for (int off = 32; off > 0; off >>= 1)
            m = fmaxf(m, __shfl_down(m, off));
        if (tid == 0) blockmax[bq] = m;
    }
}

// ---------------------------------------------------------------------------
// Fixup: C = where(finite, C, 2*max_finite) per batch. Fast path: no-op.
// ---------------------------------------------------------------------------
__global__ __launch_bounds__(256) void fix_kernel(float* __restrict__ out,
                                                  const float* __restrict__ blockmax)
{
    __shared__ int bad;
    int tid = threadIdx.x;
    int i = blockIdx.x * 256 + tid;
    bool active = (i < BS * QN * TN);
    float v = active ? out[i] : 0.0f;
    if (tid == 0) bad = 0;
    __syncthreads();
    if (!isfinite(v)) bad = 1;   // benign same-value race
    __syncthreads();
    if (!bad) return;            // uniform across block
    if (!isfinite(v)) {
        int b = i / (QN * TN);
        float m = -INFINITY;
        for (int k = 0; k < QN; ++k) m = fmaxf(m, blockmax[b * QN + k]);
        out[i] = 2.0f * m;
    }
}

extern "C" void kernel_launch(void* const* d_in, const int* in_sizes, int n_in,
                              void* d_out, int out_size, void* d_ws, size_t ws_size,
                              hipStream_t stream) {
    const float* logits  = (const float*)d_in[0];
    const float4* pboxes = (const float4*)d_in[1];
    const int* labels    = (const int*)d_in[2];
    const float4* tboxes = (const float4*)d_in[3];
    const float* pmasks  = (const float*)d_in[4];
    const int* tmasks    = (const int*)d_in[5];
    const float* coords  = (const float*)d_in[6];
    float* out = (float*)d_out;

    char* ws = (char*)d_ws;
    unsigned* tmw   = (unsigned*)(ws);            // 25600 B
    float* tmsum    = (float*)(ws + 25600);       // 800 B
    float* blockmax = (float*)(ws + 26400);       // 7200 B

    hipLaunchKernelGGL(prep_kernel, dim3(BS * TN), dim3(256), 0, stream,
                       (const float2*)coords, tmasks, tmw, tmsum);
    hipLaunchKernelGGL(main_kernel, dim3(BS * QN), dim3(256), 0, stream,
                       logits, pboxes, labels, tboxes, pmasks, (const float2*)coords,
                       tmw, tmsum, out, blockmax);
    hipLaunchKernelGGL(fix_kernel, dim3((BS * QN * TN + 255) / 256), dim3(256), 0, stream,
                       out, blockmax);
}